// Round 8
// baseline (927.616 us; speedup 1.0000x reference)
//
#include <hip/hip_runtime.h>
#include <hip/hip_bf16.h>

typedef unsigned short u16;
typedef unsigned int u32;
typedef unsigned long long u64;
typedef __attribute__((ext_vector_type(8))) short short8;
typedef __attribute__((ext_vector_type(4))) float f32x4;

#define TOKENS 4096
#define HDIM 2048
#define NEXP 16
#define IDIM 1024
#define ISH 2048
#define NCHUNK 128  // 8192 route entries / 64 lanes

// merged GEMM work lists
#define GUITEMS 2304  // 32*32 shared + <=80*16 routed
#define GUCHUNK 288   // GUITEMS/8
#define DITEMS 2048   // 16*32 shared + <=48*32 routed
#define DCHUNK 256    // DITEMS/8

#define AS1(p) ((const __attribute__((address_space(1))) u32*)(p))
#define AS3(p) ((__attribute__((address_space(3))) u32*)(p))

__device__ __forceinline__ u16 f2b(float f) {
    u32 u = __float_as_uint(f);
    u32 r = u + 0x7fffu + ((u >> 16) & 1u);
    return (u16)(r >> 16);
}

// ---------------- convert x to bf16 ----------------
__global__ __launch_bounds__(256) void convert_x_kernel(const float* __restrict__ x,
                                                        u16* __restrict__ xb) {
    size_t i = ((size_t)blockIdx.x * 256 + threadIdx.x) * 8;
    float4 a = *(const float4*)(x + i);
    float4 b = *(const float4*)(x + i + 4);
    u32 p0 = (u32)f2b(a.x) | ((u32)f2b(a.y) << 16);
    u32 p1 = (u32)f2b(a.z) | ((u32)f2b(a.w) << 16);
    u32 p2 = (u32)f2b(b.x) | ((u32)f2b(b.y) << 16);
    u32 p3 = (u32)f2b(b.z) | ((u32)f2b(b.w) << 16);
    uint4 o = make_uint4(p0, p1, p2, p3);
    *(uint4*)(xb + i) = o;
}

// ---------------- routing: 1 wave per token, cent staged in LDS ----------------
__global__ __launch_bounds__(256) void route_kernel(const float* __restrict__ x,
                                                    const float* __restrict__ cent,
                                                    const float* __restrict__ bias,
                                                    int* __restrict__ top_e,
                                                    float* __restrict__ top_w) {
    __shared__ alignas(16) float cs[8 * 2048];  // 64KB: 8 experts per phase
    int lane = threadIdx.x & 63;
    int wv = threadIdx.x >> 6;
    int t = blockIdx.x * 4 + wv;
    const float4* xp4 = (const float4*)(x + (size_t)t * HDIM);
    float4 xr[8];
#pragma unroll
    for (int i = 0; i < 8; i++) xr[i] = xp4[lane + 64 * i];
    float aff[16];
#pragma unroll
    for (int ph = 0; ph < 2; ph++) {
        if (ph) __syncthreads();
        const float* sbase = cent + (size_t)(ph * 8 + wv * 2) * HDIM;
        float* dbase = cs + (size_t)wv * 2 * HDIM;
#pragma unroll
        for (int i = 0; i < 16; i++) {
            __builtin_amdgcn_global_load_lds(AS1(sbase + i * 256 + lane * 4),
                                             AS3(dbase + i * 256), 16, 0, 0);
        }
        __syncthreads();
#pragma unroll
        for (int e = 0; e < 8; e++) {
            const float4* cp = (const float4*)cs + (size_t)e * 512;
            float s = 0.f;
#pragma unroll
            for (int i = 0; i < 8; i++) {
                float4 cv = cp[lane + 64 * i];
                s += xr[i].x * cv.x;
                s += xr[i].y * cv.y;
                s += xr[i].z * cv.z;
                s += xr[i].w * cv.w;
            }
#pragma unroll
            for (int off = 32; off > 0; off >>= 1) s += __shfl_xor(s, off, 64);
            aff[ph * 8 + e] = 1.f / (1.f + expf(-s));
        }
    }
    float b0 = -1e30f, b1 = -1e30f, a0 = 0.f, a1 = 0.f;
    int e0 = -1, e1 = -1;
#pragma unroll
    for (int e = 0; e < 16; e++) {
        float v = aff[e] + bias[e];
        if (v > b0) {
            b1 = b0; e1 = e0; a1 = a0;
            b0 = v; e0 = e; a0 = aff[e];
        } else if (v > b1) {
            b1 = v; e1 = e; a1 = aff[e];
        }
    }
    float inv = 1.f / (a0 + a1 + 1e-9f);
    if (lane == 0) {
        top_e[2 * t] = e0; top_w[2 * t] = a0 * inv;
        top_e[2 * t + 1] = e1; top_w[2 * t + 1] = a1 * inv;
    }
}

// ---------------- build: histogram + scan + work-item lists + scatter ----------
// Items: (routed<<28)|(e<<20)|(mtile<<8)|yblock, -1 = dead. Ordered in
// (4-tile x 4-ypanel) supertiles so an XCD's contiguous chunk has a ~4MB
// working set (fits per-XCD L2).
__global__ __launch_bounds__(1024) void build_kernel(
    const int* __restrict__ top_e, const float* __restrict__ top_w,
    int* __restrict__ counts, int* __restrict__ offsets, int* __restrict__ itemsGU,
    int* __restrict__ itemsD, int* __restrict__ list_tok, int* __restrict__ tok2slot) {
    __shared__ int cnt[NCHUNK][16];
    __shared__ int offs_s[16];
    __shared__ int totals[16];
    __shared__ int guPref[16], dPref[16];
    int tid = threadIdx.x;
    int lane = tid & 63, wv = tid >> 6;  // 16 waves
    // fill item lists with -1 (before first barrier; rewritten below)
    for (int i = tid; i < GUITEMS; i += 1024) itemsGU[i] = -1;
    for (int i = tid; i < DITEMS; i += 1024) itemsD[i] = -1;
    // phase 1: per-chunk histograms via ballot
    for (int c = wv; c < NCHUNK; c += 16) {
        int v = top_e[c * 64 + lane];
#pragma unroll
        for (int e = 0; e < 16; e++) {
            u64 m = __ballot(v == e);
            if (lane == 0) cnt[c][e] = (int)__popcll(m);
        }
    }
    __syncthreads();
    if (tid < 16) {
        int s = 0;
        for (int c = 0; c < NCHUNK; c++) s += cnt[c][tid];
        totals[tid] = s;
        counts[tid] = s;
    }
    __syncthreads();
    if (tid == 0) {
        int r = 0, g = 0, d = 0;
        for (int e = 0; e < 16; e++) {
            offs_s[e] = r;
            offsets[e] = r;
            r += totals[e];
            guPref[e] = g;
            g += ((totals[e] + 127) >> 7) * 16;
            dPref[e] = d;
            d += ((totals[e] + 255) >> 8) * 32;
        }
    }
    // shared-GEMM items (static formulas)
    {
        int i = tid;  // GU shared: 1024 items, supertile (4m x 4y)
        int g = i >> 4, s = i & 15;
        int y0 = (g >> 3) << 2, m0 = (g & 7) << 2;
        itemsGU[i] = ((m0 + (s >> 2)) << 8) | (y0 + (s & 3));
    }
    if (tid < 512) {  // D shared: 512 items
        int i = tid;
        int g = i >> 4, s = i & 15;
        int y0 = (g >> 2) << 2, m0 = (g & 3) << 2;
        itemsD[i] = ((m0 + (s >> 2)) << 8) | (y0 + (s & 3));
    }
    __syncthreads();
    // routed items + per-chunk bases (16 threads)
    if (tid < 16) {
        int e = tid;
        int tA = (totals[e] + 127) >> 7;
        int p = 1024 + guPref[e];
        for (int y0 = 0; y0 < 16; y0 += 4)
            for (int m = 0; m < tA; m++)
                for (int dy = 0; dy < 4; dy++)
                    itemsGU[p++] = (1 << 28) | (e << 20) | (m << 8) | (y0 + dy);
        int tB = (totals[e] + 255) >> 8;
        p = 512 + dPref[e];
        for (int y0 = 0; y0 < 32; y0 += 4)
            for (int m = 0; m < tB; m++)
                for (int dy = 0; dy < 4; dy++)
                    itemsD[p++] = (1 << 28) | (e << 20) | (m << 8) | (y0 + dy);
        int r = offs_s[e];
        for (int c = 0; c < NCHUNK; c++) {
            int v = cnt[c][e];
            cnt[c][e] = r;
            r += v;
        }
    }
    __syncthreads();
    // scatter entries to slots (rank via ballot)
    for (int c = wv; c < NCHUNK; c += 16) {
        int i = c * 64 + lane;
        int v = top_e[i];
        int rank = 0;
#pragma unroll
        for (int e = 0; e < 16; e++) {
            u64 m = __ballot(v == e);
            if (v == e) rank = (int)__popcll(m & ((1ull << lane) - 1ull));
        }
        int slot = cnt[c][v] + rank;
        list_tok[slot] = i >> 1;
        tok2slot[i] = slot;
    }
}

// ================= MAIN PATH =================
// Convert fp32 W[K][N] -> bf16 tiled [N/64][K/32][64][32] with XOR swizzle.
// Two source/dest pairs selected by blockIdx.z (merged dispatches).
__global__ __launch_bounds__(256) void conv_w_kernel(const float* __restrict__ W,
                                                     const float* __restrict__ W2,
                                                     u16* __restrict__ Wt,
                                                     u16* __restrict__ Wt2, int K, int N,
                                                     int zsplit) {
    int nt = blockIdx.x, kc = blockIdx.y;
    int zz = blockIdx.z;
    const float* Wm;
    u16* Wtm;
    if (zz < zsplit) {
        Wm = W + (size_t)zz * K * N;
        Wtm = Wt + (size_t)zz * K * N;
    } else {
        int z2 = zz - zsplit;
        Wm = W2 + (size_t)z2 * K * N;
        Wtm = Wt2 + (size_t)z2 * K * N;
    }
    int ksB = K >> 5;
    __shared__ u16 Ls[64 * 40];
    int t = threadIdx.x;
    int kr = t >> 3, ng = t & 7;
    int nn = t >> 2, seg = t & 3;
    int g = seg ^ ((nn >> 2) & 3);
#pragma unroll
    for (int s = 0; s < 8; s++) {
        int kb = kc * 256 + s * 32;
        const float* src = Wm + (size_t)(kb + kr) * N + nt * 64 + ng * 8;
        float4 f0 = *(const float4*)src;
        float4 f1 = *(const float4*)(src + 4);
        __syncthreads();
        const float* p0 = (const float*)&f0;
        const float* p1 = (const float*)&f1;
#pragma unroll
        for (int l = 0; l < 4; l++) Ls[(8 * ng + l) * 40 + kr] = f2b(p0[l]);
#pragma unroll
        for (int l = 0; l < 4; l++) Ls[(8 * ng + 4 + l) * 40 + kr] = f2b(p1[l]);
        __syncthreads();
        const u16* lp = &Ls[nn * 40 + g * 8];
        u32 w0 = (u32)lp[0] | ((u32)lp[1] << 16);
        u32 w1 = (u32)lp[2] | ((u32)lp[3] << 16);
        u32 w2 = (u32)lp[4] | ((u32)lp[5] << 16);
        u32 w3 = (u32)lp[6] | ((u32)lp[7] << 16);
        uint4 o = make_uint4(w0, w1, w2, w3);
        *(uint4*)(Wtm + (size_t)(nt * ksB + (kb >> 5)) * 2048 + t * 8) = o;
    }
}

// merged fused gate+up (shared + routed): M-tile 128, N-tile 64, BK 64.
// Work-item-list grid with chunked XCD swizzle; inner loop = round-7 verified.
__global__ __launch_bounds__(256) void gemm_gateup(
    const u16* __restrict__ A, const u16* __restrict__ BgS, const u16* __restrict__ BuS,
    const u16* __restrict__ BgR, const u16* __restrict__ BuR, u16* __restrict__ hS,
    u16* __restrict__ hR, const int* __restrict__ counts, const int* __restrict__ offsets,
    const int* __restrict__ list_tok, const int* __restrict__ items) {
    int idx = (blockIdx.x & 7) * GUCHUNK + (blockIdx.x >> 3);
    int it = items[idx];
    if (it < 0) return;
    int routed = (it >> 28) & 1;
    int e = (it >> 20) & 15;
    int m0 = ((it >> 8) & 4095) * 128;
    int yb = it & 255;
    int cnt, base, Nout;
    const u16 *Bg, *Bu;
    u16* hout;
    if (routed) {
        cnt = counts[e];
        base = offsets[e];
        Nout = IDIM;
        size_t off = (size_t)e * HDIM * IDIM;
        Bg = BgR + off;
        Bu = BuR + off;
        hout = hR;
    } else {
        cnt = TOKENS;
        base = 0;
        Nout = ISH;
        Bg = BgS;
        Bu = BuS;
        hout = hS;
    }
    const int nk = HDIM >> 6;  // BK=64 steps
    __shared__ alignas(16) u16 As[128 * 64];   // chunk c at c*4096 (128r x 32k)
    __shared__ alignas(16) u16 Bgs[64 * 64];   // chunk c at c*2048 (64n x 32k)
    __shared__ alignas(16) u16 Bus[64 * 64];
    int tid = threadIdx.x;
    int lane = tid & 63, wv = tid >> 6;
    int quad = lane >> 4, mr = lane & 15;
    int n0 = yb * 64;
    int gk = (tid & 3) ^ ((tid >> 4) & 3);
    int mg0 = min(m0 + (tid >> 2), cnt - 1);
    int mg1 = min(m0 + 64 + (tid >> 2), cnt - 1);
    size_t sr0 = routed ? (size_t)list_tok[base + mg0] : (size_t)mg0;
    size_t sr1 = routed ? (size_t)list_tok[base + mg1] : (size_t)mg1;
    const u16* ap0 = A + sr0 * HDIM + gk * 8;
    const u16* ap1 = A + sr1 * HDIM + gk * 8;
    size_t bstr = (size_t)(HDIM >> 5) * 2048;
    const u16* bgp = Bg + (size_t)yb * bstr + tid * 8;
    const u16* bup = Bu + (size_t)yb * bstr + tid * 8;
    int xq = quad ^ ((mr >> 2) & 3);
    f32x4 accg[2][4], accu[2][4];
#pragma unroll
    for (int i = 0; i < 2; i++)
#pragma unroll
        for (int j = 0; j < 4; j++) { accg[i][j] = (f32x4)0.f; accu[i][j] = (f32x4)0.f; }

    for (int ks = 0; ks < nk; ks++) {
        __syncthreads();
        __builtin_amdgcn_global_load_lds(AS1(ap0), AS3(As + wv * 512), 16, 0, 0);
        __builtin_amdgcn_global_load_lds(AS1(ap0 + 32), AS3(As + 4096 + wv * 512), 16, 0, 0);
        __builtin_amdgcn_global_load_lds(AS1(ap1), AS3(As + 2048 + wv * 512), 16, 0, 0);
        __builtin_amdgcn_global_load_lds(AS1(ap1 + 32), AS3(As + 6144 + wv * 512), 16, 0, 0);
        __builtin_amdgcn_global_load_lds(AS1(bgp), AS3(Bgs + wv * 512), 16, 0, 0);
        __builtin_amdgcn_global_load_lds(AS1(bgp + 2048), AS3(Bgs + 2048 + wv * 512), 16, 0, 0);
        __builtin_amdgcn_global_load_lds(AS1(bup), AS3(Bus + wv * 512), 16, 0, 0);
        __builtin_amdgcn_global_load_lds(AS1(bup + 2048), AS3(Bus + 2048 + wv * 512), 16, 0, 0);
        ap0 += 64; ap1 += 64; bgp += 4096; bup += 4096;
        __syncthreads();
#pragma unroll
        for (int c = 0; c < 2; c++) {
            short8 a0 = *(const short8*)(As + c * 4096 + ((32 * wv + mr) * 4 + xq) * 8);
            short8 a1 = *(const short8*)(As + c * 4096 + ((32 * wv + 16 + mr) * 4 + xq) * 8);
#pragma unroll
            for (int j = 0; j < 4; j++) {
                short8 bg = *(const short8*)(Bgs + c * 2048 + (64 * j + mr * 4 + xq) * 8);
                short8 bu = *(const short8*)(Bus + c * 2048 + (64 * j + mr * 4 + xq) * 8);
                accg[0][j] = __builtin_amdgcn_mfma_f32_16x16x32_bf16(a0, bg, accg[0][j], 0, 0, 0);
                accg[1][j] = __builtin_amdgcn_mfma_f32_16x16x32_bf16(a1, bg, accg[1][j], 0, 0, 0);
                accu[0][j] = __builtin_amdgcn_mfma_f32_16x16x32_bf16(a0, bu, accu[0][j], 0, 0, 0);
                accu[1][j] = __builtin_amdgcn_mfma_f32_16x16x32_bf16(a1, bu, accu[1][j], 0, 0, 0);
            }
        }
    }
#pragma unroll
    for (int i = 0; i < 2; i++)
#pragma unroll
        for (int j = 0; j < 4; j++)
#pragma unroll
            for (int r = 0; r < 4; r++) {
                int m = m0 + 32 * wv + 16 * i + quad * 4 + r;
                if (m < cnt) {
                    float gv = accg[i][j][r], uv = accu[i][j][r];
                    float h = gv / (1.f + expf(-gv)) * uv;
                    int n = n0 + 16 * j + mr;
                    hout[(size_t)(base + m) * Nout + n] = f2b(h);
                }
            }
}

// merged down GEMM (shared + routed): M-tile 256, N-tile 64, BK 64.
__global__ __launch_bounds__(256) void gemm_down(
    const u16* __restrict__ hS, const u16* __restrict__ hR, const u16* __restrict__ BdS,
    const u16* __restrict__ BdR, float* __restrict__ out, float* __restrict__ rd,
    const int* __restrict__ counts, const int* __restrict__ offsets,
    const int* __restrict__ items) {
    int idx = (blockIdx.x & 7) * DCHUNK + (blockIdx.x >> 3);
    int it = items[idx];
    if (it < 0) return;
    int routed = (it >> 28) & 1;
    int e = (it >> 20) & 15;
    int m0 = ((it >> 8) & 4095) * 256;
    int yb = it & 255;
    int cnt, base, Kd;
    const u16 *A, *B;
    float* outp;
    if (routed) {
        cnt = counts[e];
        base = offsets[e];
        Kd = IDIM;
        A = hR;
        B = BdR + (size_t)e * IDIM * HDIM;
        outp = rd;
    } else {
        cnt = TOKENS;
        base = 0;
        Kd = ISH;
        A = hS;
        B = BdS;
        outp = out;
    }
    int nk = Kd >> 6;  // BK=64
    __shared__ alignas(16) u16 As[256 * 64];  // 32 KB: chunk c at c*8192
    __shared__ alignas(16) u16 Bs[64 * 64];   // 8 KB: chunk c at c*2048
    int tid = threadIdx.x;
    int lane = tid & 63, wv = tid >> 6;
    int quad = lane >> 4, mr = lane & 15;
    int n0 = yb * 64;
    int gk = (tid & 3) ^ ((tid >> 4) & 3);
    const u16* ap0;
    const u16* ap1;
    const u16* ap2;
    const u16* ap3;
    {
        int mg0 = base + min(m0 + 0 * 64 + (tid >> 2), cnt - 1);
        int mg1 = base + min(m0 + 1 * 64 + (tid >> 2), cnt - 1);
        int mg2 = base + min(m0 + 2 * 64 + (tid >> 2), cnt - 1);
        int mg3 = base + min(m0 + 3 * 64 + (tid >> 2), cnt - 1);
        ap0 = A + (size_t)mg0 * Kd + gk * 8;
        ap1 = A + (size_t)mg1 * Kd + gk * 8;
        ap2 = A + (size_t)mg2 * Kd + gk * 8;
        ap3 = A + (size_t)mg3 * Kd + gk * 8;
    }
    size_t bstr = (size_t)(Kd >> 5) * 2048;
    const u16* bp = B + (size_t)yb * bstr + tid * 8;
    int xq = quad ^ ((mr >> 2) & 3);
    f32x4 acc[4][4];
#pragma unroll
    for (int i = 0; i < 4; i++)
#pragma unroll
        for (int j = 0; j < 4; j++) acc[i][j] = (f32x4)0.f;

    for (int ks = 0; ks < nk; ks++) {
        __syncthreads();
        __builtin_amdgcn_global_load_lds(AS1(ap0), AS3(As + 0 + wv * 512), 16, 0, 0);
        __builtin_amdgcn_global_load_lds(AS1(ap0 + 32), AS3(As + 8192 + wv * 512), 16, 0, 0);
        __builtin_amdgcn_global_load_lds(AS1(ap1), AS3(As + 2048 + wv * 512), 16, 0, 0);
        __builtin_amdgcn_global_load_lds(AS1(ap1 + 32), AS3(As + 10240 + wv * 512), 16, 0, 0);
        __builtin_amdgcn_global_load_lds(AS1(ap2), AS3(As + 4096 + wv * 512), 16, 0, 0);
        __builtin_amdgcn_global_load_lds(AS1(ap2 + 32), AS3(As + 12288 + wv * 512), 16, 0, 0);
        __builtin_amdgcn_global_load_lds(AS1(ap3), AS3(As + 6144 + wv * 512), 16, 0, 0);
        __builtin_amdgcn_global_load_lds(AS1(ap3 + 32), AS3(As + 14336 + wv * 512), 16, 0, 0);
        __builtin_amdgcn_global_load_lds(AS1(bp), AS3(Bs + wv * 512), 16, 0, 0);
        __builtin_amdgcn_global_load_lds(AS1(bp + 2048), AS3(Bs + 2048 + wv * 512), 16, 0, 0);
        ap0 += 64; ap1 += 64; ap2 += 64; ap3 += 64; bp += 4096;
        __syncthreads();
#pragma unroll
        for (int c = 0; c < 2; c++) {
            short8 a0 = *(const short8*)(As + c * 8192 + ((64 * wv + 0 + mr) * 4 + xq) * 8);
            short8 a1 = *(const short8*)(As + c * 8192 + ((64 * wv + 16 + mr) * 4 + xq) * 8);
            short8 a2 = *(const short8*)(As + c * 8192 + ((64 * wv + 32 + mr) * 4 + xq) * 8);
            short8 a3 = *(const short8*)(As + c * 8192 + ((64 * wv + 48 + mr) * 4 + xq) * 8);
#pragma unroll
            for (int j = 0; j < 4; j++) {
                short8 b = *(const short8*)(Bs + c * 2048 + (64 * j + mr * 4 + xq) * 8);
                acc[0][j] = __builtin_amdgcn_mfma_f32_16x16x32_bf16(a0, b, acc[0][j], 0, 0, 0);
                acc[1][j] = __builtin_amdgcn_mfma_f32_16x16x32_bf16(a1, b, acc[1][j], 0, 0, 0);
                acc[2][j] = __builtin_amdgcn_mfma_f32_16x16x32_bf16(a2, b, acc[2][j], 0, 0, 0);
                acc[3][j] = __builtin_amdgcn_mfma_f32_16x16x32_bf16(a3, b, acc[3][j], 0, 0, 0);
            }
        }
    }

#pragma unroll
    for (int i = 0; i < 4; i++)
#pragma unroll
        for (int j = 0; j < 4; j++)
#pragma unroll
            for (int r = 0; r < 4; r++) {
                int m = m0 + 64 * wv + 16 * i + quad * 4 + r;
                if (m >= cnt) continue;
                int n = n0 + 16 * j + mr;
                float v = acc[i][j][r];
                if (routed) {
                    outp[(size_t)(base + m) * HDIM + n] = v;  // per-slot, no atomics
                } else {
                    outp[(size_t)m * HDIM + n] = 0.1f * v;
                }
            }
}

// ---------------- combine: out[t] += w0*rd[slot0] + w1*rd[slot1] ----------------
__global__ __launch_bounds__(256) void combine_kernel(float* __restrict__ out,
                                                      const float* __restrict__ rd,
                                                      const int* __restrict__ tok2slot,
                                                      const float* __restrict__ top_w) {
    int t = blockIdx.x;
    int s0 = tok2slot[2 * t], s1 = tok2slot[2 * t + 1];
    float w0 = top_w[2 * t], w1 = top_w[2 * t + 1];
    const float4* r0 = (const float4*)(rd + (size_t)s0 * HDIM);
    const float4* r1 = (const float4*)(rd + (size_t)s1 * HDIM);
    float4* op = (float4*)(out + (size_t)t * HDIM);
#pragma unroll
    for (int k = 0; k < 2; k++) {
        int c = threadIdx.x + k * 256;
        float4 o = op[c];
        float4 a = r0[c];
        float4 b = r1[c];
        o.x += w0 * a.x + w1 * b.x;
        o.y += w0 * a.y + w1 * b.y;
        o.z += w0 * a.z + w1 * b.z;
        o.w += w0 * a.w + w1 * b.w;
        op[c] = o;
    }
}

extern "C" void kernel_launch(void* const* d_in, const int* in_sizes, int n_in,
                              void* d_out, int out_size, void* d_ws, size_t ws_size,
                              hipStream_t stream) {
    const float* x = (const float*)d_in[0];
    const float* cent = (const float*)d_in[1];
    const float* bias = (const float*)d_in[2];
    const float* wgs = (const float*)d_in[3];
    const float* wus = (const float*)d_in[4];
    const float* wds = (const float*)d_in[5];
    const float* wg = (const float*)d_in[6];
    const float* wu = (const float*)d_in[7];
    const float* wd = (const float*)d_in[8];
    float* out = (float*)d_out;
    char* ws = (char*)d_ws;

    size_t off_wtgs = 0;
    size_t off_wtus = off_wtgs + (size_t)HDIM * ISH * 2;
    size_t off_wtds = off_wtus + (size_t)HDIM * ISH * 2;
    size_t off_wtg = off_wtds + (size_t)ISH * HDIM * 2;
    size_t off_wtu = off_wtg + (size_t)NEXP * HDIM * IDIM * 2;
    size_t off_wtd = off_wtu + (size_t)NEXP * HDIM * IDIM * 2;
    size_t off_xbf = off_wtd + (size_t)NEXP * IDIM * HDIM * 2;
    size_t off_hsh = off_xbf + (size_t)TOKENS * HDIM * 2;
    size_t off_hrt = off_hsh + (size_t)TOKENS * ISH * 2;
    size_t off_meta = off_hrt + (size_t)2 * TOKENS * IDIM * 2;
    size_t need = off_meta + (1 << 20);
    if (ws_size < need) return;  // main path verified present in round 2

    u16* Wt_gs = (u16*)(ws + off_wtgs);
    u16* Wt_us = (u16*)(ws + off_wtus);
    u16* Wt_ds = (u16*)(ws + off_wtds);
    u16* Wt_g = (u16*)(ws + off_wtg);
    u16* Wt_u = (u16*)(ws + off_wtu);
    u16* Wt_d = (u16*)(ws + off_wtd);
    u16* x_bf = (u16*)(ws + off_xbf);
    u16* h_sh = (u16*)(ws + off_hsh);
    u16* h_rt = (u16*)(ws + off_hrt);
    // rd (67 MB, f32 [8192][2048]) OVERLAPS Wt_gs/Wt_us/Wt_ds + head of Wt_g:
    // every reader of those (merged gateup reads them; merged down reads only
    // Wt_ds before any rd write... note: merged down reads Wt_ds (inside the
    // overlap) while ALSO writing rd. To avoid that intra-dispatch alias, rd
    // is placed at off_wtg (overlapping routed gate/up weights only, whose
    // last reader is the gateup dispatch that precedes gemm_down).
    float* rd = (float*)(ws + off_wtg);
    int* counts = (int*)(ws + off_meta);
    int* offsets = counts + 16;
    int* itemsGU = offsets + 16;
    int* itemsD = itemsGU + GUITEMS;
    int* tok2slot = itemsD + DITEMS;
    int* top_e = tok2slot + 2 * TOKENS;
    float* top_w = (float*)(top_e + 2 * TOKENS);
    int* list_tok = (int*)(top_w + 2 * TOKENS);

    convert_x_kernel<<<TOKENS * HDIM / (256 * 8), 256, 0, stream>>>(x, x_bf);
    route_kernel<<<TOKENS / 4, 256, 0, stream>>>(x, cent, bias, top_e, top_w);
    build_kernel<<<1, 1024, 0, stream>>>(top_e, top_w, counts, offsets, itemsGU, itemsD,
                                         list_tok, tok2slot);

    // weight conversions (merged where shapes match)
    conv_w_kernel<<<dim3(ISH / 64, HDIM / 256, 2), 256, 0, stream>>>(
        wgs, wus, Wt_gs, Wt_us, HDIM, ISH, 1);
    conv_w_kernel<<<dim3(HDIM / 64, ISH / 256, 1), 256, 0, stream>>>(
        wds, wds, Wt_ds, Wt_ds, ISH, HDIM, 1);
    conv_w_kernel<<<dim3(IDIM / 64, HDIM / 256, 2 * NEXP), 256, 0, stream>>>(
        wg, wu, Wt_g, Wt_u, HDIM, IDIM, NEXP);
    conv_w_kernel<<<dim3(HDIM / 64, IDIM / 256, NEXP), 256, 0, stream>>>(
        wd, wd, Wt_d, Wt_d, IDIM, HDIM, NEXP);

    // merged GEMMs (shared + routed in one dispatch each)
    gemm_gateup<<<GUITEMS, 256, 0, stream>>>(x_bf, Wt_gs, Wt_us, Wt_g, Wt_u, h_sh, h_rt,
                                             counts, offsets, list_tok, itemsGU);
    gemm_down<<<DITEMS, 256, 0, stream>>>(h_sh, h_rt, Wt_ds, Wt_d, out, rd, counts,
                                          offsets, itemsD);
    combine_kernel<<<TOKENS, 256, 0, stream>>>(out, rd, tok2slot, top_w);
}

// Round 9
// 865.757 us; speedup vs baseline: 1.0715x; 1.0715x over previous
//
#include <hip/hip_runtime.h>
#include <hip/hip_bf16.h>

typedef unsigned short u16;
typedef unsigned int u32;
typedef unsigned long long u64;
typedef __attribute__((ext_vector_type(8))) short short8;
typedef __attribute__((ext_vector_type(4))) float f32x4;

#define TOKENS 4096
#define HDIM 2048
#define NEXP 16
#define IDIM 1024
#define ISH 2048
#define NCHUNK 128  // 8192 route entries / 64 lanes

// merged GEMM work lists (16-item supertiles; counts divisible by 128)
#define GUITEMS 2304  // 144 supertiles = 8 XCD groups x 18
#define DITEMS 2048   // 128 supertiles = 8 x 16

#define AS1(p) ((const __attribute__((address_space(1))) u32*)(p))
#define AS3(p) ((__attribute__((address_space(3))) u32*)(p))

__device__ __forceinline__ u16 f2b(float f) {
    u32 u = __float_as_uint(f);
    u32 r = u + 0x7fffu + ((u >> 16) & 1u);
    return (u16)(r >> 16);
}

// supertile round-robin: supertile s -> XCD s%8 (keeps 16-item supertile on one
// XCD for L2 reuse; spreads shared/routed/dead supertiles evenly across XCDs)
__device__ __forceinline__ int item_index(int bid) {
    int x = bid & 7, j = bid >> 3;
    return ((x + 8 * (j >> 4)) << 4) | (j & 15);
}

// ---------------- routing: 1 wave per token; ALSO emits x_bf (fused convert) --
__global__ __launch_bounds__(256) void route_kernel(const float* __restrict__ x,
                                                    const float* __restrict__ cent,
                                                    const float* __restrict__ bias,
                                                    u16* __restrict__ xb,
                                                    int* __restrict__ top_e,
                                                    float* __restrict__ top_w) {
    __shared__ alignas(16) float cs[8 * 2048];  // 64KB: 8 experts per phase
    int lane = threadIdx.x & 63;
    int wv = threadIdx.x >> 6;
    int t = blockIdx.x * 4 + wv;
    const float4* xp4 = (const float4*)(x + (size_t)t * HDIM);
    float4 xr[8];
#pragma unroll
    for (int i = 0; i < 8; i++) xr[i] = xp4[lane + 64 * i];
    // fused convert: store this token row as bf16 (row already in registers)
    u16* xbp = xb + (size_t)t * HDIM;
#pragma unroll
    for (int i = 0; i < 8; i++) {
        u32 lo = (u32)f2b(xr[i].x) | ((u32)f2b(xr[i].y) << 16);
        u32 hi = (u32)f2b(xr[i].z) | ((u32)f2b(xr[i].w) << 16);
        uint2 o = make_uint2(lo, hi);
        *(uint2*)(xbp + (size_t)(lane + 64 * i) * 4) = o;
    }
    float aff[16];
#pragma unroll
    for (int ph = 0; ph < 2; ph++) {
        if (ph) __syncthreads();
        const float* sbase = cent + (size_t)(ph * 8 + wv * 2) * HDIM;
        float* dbase = cs + (size_t)wv * 2 * HDIM;
#pragma unroll
        for (int i = 0; i < 16; i++) {
            __builtin_amdgcn_global_load_lds(AS1(sbase + i * 256 + lane * 4),
                                             AS3(dbase + i * 256), 16, 0, 0);
        }
        __syncthreads();
#pragma unroll
        for (int e = 0; e < 8; e++) {
            const float4* cp = (const float4*)cs + (size_t)e * 512;
            float s = 0.f;
#pragma unroll
            for (int i = 0; i < 8; i++) {
                float4 cv = cp[lane + 64 * i];
                s += xr[i].x * cv.x;
                s += xr[i].y * cv.y;
                s += xr[i].z * cv.z;
                s += xr[i].w * cv.w;
            }
#pragma unroll
            for (int off = 32; off > 0; off >>= 1) s += __shfl_xor(s, off, 64);
            aff[ph * 8 + e] = 1.f / (1.f + expf(-s));
        }
    }
    float b0 = -1e30f, b1 = -1e30f, a0 = 0.f, a1 = 0.f;
    int e0 = -1, e1 = -1;
#pragma unroll
    for (int e = 0; e < 16; e++) {
        float v = aff[e] + bias[e];
        if (v > b0) {
            b1 = b0; e1 = e0; a1 = a0;
            b0 = v; e0 = e; a0 = aff[e];
        } else if (v > b1) {
            b1 = v; e1 = e; a1 = aff[e];
        }
    }
    float inv = 1.f / (a0 + a1 + 1e-9f);
    if (lane == 0) {
        top_e[2 * t] = e0; top_w[2 * t] = a0 * inv;
        top_e[2 * t + 1] = e1; top_w[2 * t + 1] = a1 * inv;
    }
}

// ---------------- build: histogram + scan + work-item lists + scatter ----------
// Items: (routed<<28)|(e<<20)|(mtile<<8)|yblock, -1 = dead.
__global__ __launch_bounds__(1024) void build_kernel(
    const int* __restrict__ top_e, const float* __restrict__ top_w,
    int* __restrict__ counts, int* __restrict__ offsets, int* __restrict__ itemsGU,
    int* __restrict__ itemsD, int* __restrict__ list_tok, int* __restrict__ tok2slot) {
    __shared__ int cnt[NCHUNK][16];
    __shared__ int offs_s[16];
    __shared__ int totals[16];
    __shared__ int guPref[16], dPref[16];
    int tid = threadIdx.x;
    int lane = tid & 63, wv = tid >> 6;  // 16 waves
    for (int i = tid; i < GUITEMS; i += 1024) itemsGU[i] = -1;
    for (int i = tid; i < DITEMS; i += 1024) itemsD[i] = -1;
    for (int c = wv; c < NCHUNK; c += 16) {
        int v = top_e[c * 64 + lane];
#pragma unroll
        for (int e = 0; e < 16; e++) {
            u64 m = __ballot(v == e);
            if (lane == 0) cnt[c][e] = (int)__popcll(m);
        }
    }
    __syncthreads();
    if (tid < 16) {
        int s = 0;
        for (int c = 0; c < NCHUNK; c++) s += cnt[c][tid];
        totals[tid] = s;
        counts[tid] = s;
    }
    __syncthreads();
    if (tid == 0) {
        int r = 0, g = 0, d = 0;
        for (int e = 0; e < 16; e++) {
            offs_s[e] = r;
            offsets[e] = r;
            r += totals[e];
            guPref[e] = g;
            g += ((totals[e] + 127) >> 7) * 16;
            dPref[e] = d;
            d += ((totals[e] + 255) >> 8) * 32;
        }
    }
    // shared-GEMM items (supertiles of 16 consecutive items)
    {
        int i = tid;  // 1024 items: supertile (4m x 4y)
        int g = i >> 4, s = i & 15;
        int y0 = (g >> 3) << 2, m0 = (g & 7) << 2;
        itemsGU[i] = ((m0 + (s >> 2)) << 8) | (y0 + (s & 3));
    }
    if (tid < 512) {
        int i = tid;
        int g = i >> 4, s = i & 15;
        int y0 = (g >> 2) << 2, m0 = (g & 3) << 2;
        itemsD[i] = ((m0 + (s >> 2)) << 8) | (y0 + (s & 3));
    }
    __syncthreads();
    // routed items + per-chunk bases (16 threads)
    if (tid < 16) {
        int e = tid;
        int tA = (totals[e] + 127) >> 7;
        int p = 1024 + guPref[e];
        for (int y0 = 0; y0 < 16; y0 += 4)
            for (int m = 0; m < tA; m++)
                for (int dy = 0; dy < 4; dy++)
                    itemsGU[p++] = (1 << 28) | (e << 20) | (m << 8) | (y0 + dy);
        int tB = (totals[e] + 255) >> 8;
        p = 512 + dPref[e];
        for (int y0 = 0; y0 < 32; y0 += 4)
            for (int m = 0; m < tB; m++)
                for (int dy = 0; dy < 4; dy++)
                    itemsD[p++] = (1 << 28) | (e << 20) | (m << 8) | (y0 + dy);
        int r = offs_s[e];
        for (int c = 0; c < NCHUNK; c++) {
            int v = cnt[c][e];
            cnt[c][e] = r;
            r += v;
        }
    }
    __syncthreads();
    for (int c = wv; c < NCHUNK; c += 16) {
        int i = c * 64 + lane;
        int v = top_e[i];
        int rank = 0;
#pragma unroll
        for (int e = 0; e < 16; e++) {
            u64 m = __ballot(v == e);
            if (v == e) rank = (int)__popcll(m & ((1ull << lane) - 1ull));
        }
        int slot = cnt[c][v] + rank;
        list_tok[slot] = i >> 1;
        tok2slot[i] = slot;
    }
}

// ================= MAIN PATH =================
// ALL weight conversions in ONE dispatch: flat grid of (matrix, nt, kc) units.
// fp32 W[K][N] -> bf16 tiled [N/64][K/32][64][32] with XOR swizzle.
__global__ __launch_bounds__(256) void conv_all_kernel(
    const float* __restrict__ wgs, const float* __restrict__ wus,
    const float* __restrict__ wds, const float* __restrict__ wg,
    const float* __restrict__ wu, const float* __restrict__ wd, u16* __restrict__ Wt_gs,
    u16* __restrict__ Wt_us, u16* __restrict__ Wt_ds, u16* __restrict__ Wt_g,
    u16* __restrict__ Wt_u, u16* __restrict__ Wt_d) {
    int id = blockIdx.x;
    const float* Wm;
    u16* Wtm;
    int K, N, nt, kc;
    if (id < 768) {  // shared: 3 x 256 units, K=2048 N=2048
        K = 2048; N = 2048;
        int seg = id >> 8, r = id & 255;
        nt = r & 31; kc = r >> 5;
        if (seg == 0) { Wm = wgs; Wtm = Wt_gs; }
        else if (seg == 1) { Wm = wus; Wtm = Wt_us; }
        else { Wm = wds; Wtm = Wt_ds; }
    } else if (id < 4864) {  // wg/wu: 2 x 16e x 128 units, K=2048 N=1024
        K = 2048; N = 1024;
        int r = id - 768;
        int m = r >> 11;
        r &= 2047;
        int e = r >> 7;
        r &= 127;
        nt = r & 15; kc = r >> 4;
        size_t off = (size_t)e * 2048 * 1024;
        if (m == 0) { Wm = wg + off; Wtm = Wt_g + off; }
        else { Wm = wu + off; Wtm = Wt_u + off; }
    } else {  // wd: 16e x 128 units, K=1024 N=2048
        K = 1024; N = 2048;
        int r = id - 4864;
        int e = r >> 7;
        r &= 127;
        nt = r & 31; kc = r >> 5;
        size_t off = (size_t)e * 1024 * 2048;
        Wm = wd + off; Wtm = Wt_d + off;
    }
    int ksB = K >> 5;
    __shared__ u16 Ls[64 * 40];
    int t = threadIdx.x;
    int kr = t >> 3, ng = t & 7;
    int nn = t >> 2, seg2 = t & 3;
    int g = seg2 ^ ((nn >> 2) & 3);
#pragma unroll
    for (int s = 0; s < 8; s++) {
        int kb = kc * 256 + s * 32;
        const float* src = Wm + (size_t)(kb + kr) * N + nt * 64 + ng * 8;
        float4 f0 = *(const float4*)src;
        float4 f1 = *(const float4*)(src + 4);
        __syncthreads();
        const float* p0 = (const float*)&f0;
        const float* p1 = (const float*)&f1;
#pragma unroll
        for (int l = 0; l < 4; l++) Ls[(8 * ng + l) * 40 + kr] = f2b(p0[l]);
#pragma unroll
        for (int l = 0; l < 4; l++) Ls[(8 * ng + 4 + l) * 40 + kr] = f2b(p1[l]);
        __syncthreads();
        const u16* lp = &Ls[nn * 40 + g * 8];
        u32 w0 = (u32)lp[0] | ((u32)lp[1] << 16);
        u32 w1 = (u32)lp[2] | ((u32)lp[3] << 16);
        u32 w2 = (u32)lp[4] | ((u32)lp[5] << 16);
        u32 w3 = (u32)lp[6] | ((u32)lp[7] << 16);
        uint4 o = make_uint4(w0, w1, w2, w3);
        *(uint4*)(Wtm + (size_t)(nt * ksB + (kb >> 5)) * 2048 + t * 8) = o;
    }
}

// merged fused gate+up (shared + routed): M-tile 128, N-tile 64, BK 64.
__global__ __launch_bounds__(256) void gemm_gateup(
    const u16* __restrict__ A, const u16* __restrict__ BgS, const u16* __restrict__ BuS,
    const u16* __restrict__ BgR, const u16* __restrict__ BuR, u16* __restrict__ hS,
    u16* __restrict__ hR, const int* __restrict__ counts, const int* __restrict__ offsets,
    const int* __restrict__ list_tok, const int* __restrict__ items) {
    int it = items[item_index(blockIdx.x)];
    if (it < 0) return;
    int routed = (it >> 28) & 1;
    int e = (it >> 20) & 15;
    int m0 = ((it >> 8) & 4095) * 128;
    int yb = it & 255;
    int cnt, base, Nout;
    const u16 *Bg, *Bu;
    u16* hout;
    if (routed) {
        cnt = counts[e];
        base = offsets[e];
        Nout = IDIM;
        size_t off = (size_t)e * HDIM * IDIM;
        Bg = BgR + off;
        Bu = BuR + off;
        hout = hR;
    } else {
        cnt = TOKENS;
        base = 0;
        Nout = ISH;
        Bg = BgS;
        Bu = BuS;
        hout = hS;
    }
    const int nk = HDIM >> 6;  // BK=64 steps
    __shared__ alignas(16) u16 As[128 * 64];
    __shared__ alignas(16) u16 Bgs[64 * 64];
    __shared__ alignas(16) u16 Bus[64 * 64];
    int tid = threadIdx.x;
    int lane = tid & 63, wv = tid >> 6;
    int quad = lane >> 4, mr = lane & 15;
    int n0 = yb * 64;
    int gk = (tid & 3) ^ ((tid >> 4) & 3);
    int mg0 = min(m0 + (tid >> 2), cnt - 1);
    int mg1 = min(m0 + 64 + (tid >> 2), cnt - 1);
    size_t sr0 = routed ? (size_t)list_tok[base + mg0] : (size_t)mg0;
    size_t sr1 = routed ? (size_t)list_tok[base + mg1] : (size_t)mg1;
    const u16* ap0 = A + sr0 * HDIM + gk * 8;
    const u16* ap1 = A + sr1 * HDIM + gk * 8;
    size_t bstr = (size_t)(HDIM >> 5) * 2048;
    const u16* bgp = Bg + (size_t)yb * bstr + tid * 8;
    const u16* bup = Bu + (size_t)yb * bstr + tid * 8;
    int xq = quad ^ ((mr >> 2) & 3);
    f32x4 accg[2][4], accu[2][4];
#pragma unroll
    for (int i = 0; i < 2; i++)
#pragma unroll
        for (int j = 0; j < 4; j++) { accg[i][j] = (f32x4)0.f; accu[i][j] = (f32x4)0.f; }

    for (int ks = 0; ks < nk; ks++) {
        __syncthreads();
        __builtin_amdgcn_global_load_lds(AS1(ap0), AS3(As + wv * 512), 16, 0, 0);
        __builtin_amdgcn_global_load_lds(AS1(ap0 + 32), AS3(As + 4096 + wv * 512), 16, 0, 0);
        __builtin_amdgcn_global_load_lds(AS1(ap1), AS3(As + 2048 + wv * 512), 16, 0, 0);
        __builtin_amdgcn_global_load_lds(AS1(ap1 + 32), AS3(As + 6144 + wv * 512), 16, 0, 0);
        __builtin_amdgcn_global_load_lds(AS1(bgp), AS3(Bgs + wv * 512), 16, 0, 0);
        __builtin_amdgcn_global_load_lds(AS1(bgp + 2048), AS3(Bgs + 2048 + wv * 512), 16, 0, 0);
        __builtin_amdgcn_global_load_lds(AS1(bup), AS3(Bus + wv * 512), 16, 0, 0);
        __builtin_amdgcn_global_load_lds(AS1(bup + 2048), AS3(Bus + 2048 + wv * 512), 16, 0, 0);
        ap0 += 64; ap1 += 64; bgp += 4096; bup += 4096;
        __syncthreads();
#pragma unroll
        for (int c = 0; c < 2; c++) {
            short8 a0 = *(const short8*)(As + c * 4096 + ((32 * wv + mr) * 4 + xq) * 8);
            short8 a1 = *(const short8*)(As + c * 4096 + ((32 * wv + 16 + mr) * 4 + xq) * 8);
#pragma unroll
            for (int j = 0; j < 4; j++) {
                short8 bg = *(const short8*)(Bgs + c * 2048 + (64 * j + mr * 4 + xq) * 8);
                short8 bu = *(const short8*)(Bus + c * 2048 + (64 * j + mr * 4 + xq) * 8);
                accg[0][j] = __builtin_amdgcn_mfma_f32_16x16x32_bf16(a0, bg, accg[0][j], 0, 0, 0);
                accg[1][j] = __builtin_amdgcn_mfma_f32_16x16x32_bf16(a1, bg, accg[1][j], 0, 0, 0);
                accu[0][j] = __builtin_amdgcn_mfma_f32_16x16x32_bf16(a0, bu, accu[0][j], 0, 0, 0);
                accu[1][j] = __builtin_amdgcn_mfma_f32_16x16x32_bf16(a1, bu, accu[1][j], 0, 0, 0);
            }
        }
    }
#pragma unroll
    for (int i = 0; i < 2; i++)
#pragma unroll
        for (int j = 0; j < 4; j++)
#pragma unroll
            for (int r = 0; r < 4; r++) {
                int m = m0 + 32 * wv + 16 * i + quad * 4 + r;
                if (m < cnt) {
                    float gv = accg[i][j][r], uv = accu[i][j][r];
                    float h = gv / (1.f + expf(-gv)) * uv;
                    int n = n0 + 16 * j + mr;
                    hout[(size_t)(base + m) * Nout + n] = f2b(h);
                }
            }
}

// merged down GEMM (shared + routed): M-tile 256, N-tile 64, BK 64.
__global__ __launch_bounds__(256) void gemm_down(
    const u16* __restrict__ hS, const u16* __restrict__ hR, const u16* __restrict__ BdS,
    const u16* __restrict__ BdR, float* __restrict__ out, float* __restrict__ rd,
    const int* __restrict__ counts, const int* __restrict__ offsets,
    const int* __restrict__ items) {
    int it = items[item_index(blockIdx.x)];
    if (it < 0) return;
    int routed = (it >> 28) & 1;
    int e = (it >> 20) & 15;
    int m0 = ((it >> 8) & 4095) * 256;
    int yb = it & 255;
    int cnt, base, Kd;
    const u16 *A, *B;
    float* outp;
    if (routed) {
        cnt = counts[e];
        base = offsets[e];
        Kd = IDIM;
        A = hR;
        B = BdR + (size_t)e * IDIM * HDIM;
        outp = rd;
    } else {
        cnt = TOKENS;
        base = 0;
        Kd = ISH;
        A = hS;
        B = BdS;
        outp = out;
    }
    int nk = Kd >> 6;  // BK=64
    __shared__ alignas(16) u16 As[256 * 64];
    __shared__ alignas(16) u16 Bs[64 * 64];
    int tid = threadIdx.x;
    int lane = tid & 63, wv = tid >> 6;
    int quad = lane >> 4, mr = lane & 15;
    int n0 = yb * 64;
    int gk = (tid & 3) ^ ((tid >> 4) & 3);
    const u16* ap0;
    const u16* ap1;
    const u16* ap2;
    const u16* ap3;
    {
        int mg0 = base + min(m0 + 0 * 64 + (tid >> 2), cnt - 1);
        int mg1 = base + min(m0 + 1 * 64 + (tid >> 2), cnt - 1);
        int mg2 = base + min(m0 + 2 * 64 + (tid >> 2), cnt - 1);
        int mg3 = base + min(m0 + 3 * 64 + (tid >> 2), cnt - 1);
        ap0 = A + (size_t)mg0 * Kd + gk * 8;
        ap1 = A + (size_t)mg1 * Kd + gk * 8;
        ap2 = A + (size_t)mg2 * Kd + gk * 8;
        ap3 = A + (size_t)mg3 * Kd + gk * 8;
    }
    size_t bstr = (size_t)(Kd >> 5) * 2048;
    const u16* bp = B + (size_t)yb * bstr + tid * 8;
    int xq = quad ^ ((mr >> 2) & 3);
    f32x4 acc[4][4];
#pragma unroll
    for (int i = 0; i < 4; i++)
#pragma unroll
        for (int j = 0; j < 4; j++) acc[i][j] = (f32x4)0.f;

    for (int ks = 0; ks < nk; ks++) {
        __syncthreads();
        __builtin_amdgcn_global_load_lds(AS1(ap0), AS3(As + 0 + wv * 512), 16, 0, 0);
        __builtin_amdgcn_global_load_lds(AS1(ap0 + 32), AS3(As + 8192 + wv * 512), 16, 0, 0);
        __builtin_amdgcn_global_load_lds(AS1(ap1), AS3(As + 2048 + wv * 512), 16, 0, 0);
        __builtin_amdgcn_global_load_lds(AS1(ap1 + 32), AS3(As + 10240 + wv * 512), 16, 0, 0);
        __builtin_amdgcn_global_load_lds(AS1(ap2), AS3(As + 4096 + wv * 512), 16, 0, 0);
        __builtin_amdgcn_global_load_lds(AS1(ap2 + 32), AS3(As + 12288 + wv * 512), 16, 0, 0);
        __builtin_amdgcn_global_load_lds(AS1(ap3), AS3(As + 6144 + wv * 512), 16, 0, 0);
        __builtin_amdgcn_global_load_lds(AS1(ap3 + 32), AS3(As + 14336 + wv * 512), 16, 0, 0);
        __builtin_amdgcn_global_load_lds(AS1(bp), AS3(Bs + wv * 512), 16, 0, 0);
        __builtin_amdgcn_global_load_lds(AS1(bp + 2048), AS3(Bs + 2048 + wv * 512), 16, 0, 0);
        ap0 += 64; ap1 += 64; ap2 += 64; ap3 += 64; bp += 4096;
        __syncthreads();
#pragma unroll
        for (int c = 0; c < 2; c++) {
            short8 a0 = *(const short8*)(As + c * 8192 + ((64 * wv + 0 + mr) * 4 + xq) * 8);
            short8 a1 = *(const short8*)(As + c * 8192 + ((64 * wv + 16 + mr) * 4 + xq) * 8);
            short8 a2 = *(const short8*)(As + c * 8192 + ((64 * wv + 32 + mr) * 4 + xq) * 8);
            short8 a3 = *(const short8*)(As + c * 8192 + ((64 * wv + 48 + mr) * 4 + xq) * 8);
#pragma unroll
            for (int j = 0; j < 4; j++) {
                short8 b = *(const short8*)(Bs + c * 2048 + (64 * j + mr * 4 + xq) * 8);
                acc[0][j] = __builtin_amdgcn_mfma_f32_16x16x32_bf16(a0, b, acc[0][j], 0, 0, 0);
                acc[1][j] = __builtin_amdgcn_mfma_f32_16x16x32_bf16(a1, b, acc[1][j], 0, 0, 0);
                acc[2][j] = __builtin_amdgcn_mfma_f32_16x16x32_bf16(a2, b, acc[2][j], 0, 0, 0);
                acc[3][j] = __builtin_amdgcn_mfma_f32_16x16x32_bf16(a3, b, acc[3][j], 0, 0, 0);
            }
        }
    }

#pragma unroll
    for (int i = 0; i < 4; i++)
#pragma unroll
        for (int j = 0; j < 4; j++)
#pragma unroll
            for (int r = 0; r < 4; r++) {
                int m = m0 + 64 * wv + 16 * i + quad * 4 + r;
                if (m >= cnt) continue;
                int n = n0 + 16 * j + mr;
                float v = acc[i][j][r];
                if (routed) {
                    outp[(size_t)(base + m) * HDIM + n] = v;  // per-slot, no atomics
                } else {
                    outp[(size_t)m * HDIM + n] = 0.1f * v;
                }
            }
}

// ---------------- combine: out[t] += w0*rd[slot0] + w1*rd[slot1] ----------------
__global__ __launch_bounds__(256) void combine_kernel(float* __restrict__ out,
                                                      const float* __restrict__ rd,
                                                      const int* __restrict__ tok2slot,
                                                      const float* __restrict__ top_w) {
    int t = blockIdx.x;
    int s0 = tok2slot[2 * t], s1 = tok2slot[2 * t + 1];
    float w0 = top_w[2 * t], w1 = top_w[2 * t + 1];
    const float4* r0 = (const float4*)(rd + (size_t)s0 * HDIM);
    const float4* r1 = (const float4*)(rd + (size_t)s1 * HDIM);
    float4* op = (float4*)(out + (size_t)t * HDIM);
#pragma unroll
    for (int k = 0; k < 2; k++) {
        int c = threadIdx.x + k * 256;
        float4 o = op[c];
        float4 a = r0[c];
        float4 b = r1[c];
        o.x += w0 * a.x + w1 * b.x;
        o.y += w0 * a.y + w1 * b.y;
        o.z += w0 * a.z + w1 * b.z;
        o.w += w0 * a.w + w1 * b.w;
        op[c] = o;
    }
}

extern "C" void kernel_launch(void* const* d_in, const int* in_sizes, int n_in,
                              void* d_out, int out_size, void* d_ws, size_t ws_size,
                              hipStream_t stream) {
    const float* x = (const float*)d_in[0];
    const float* cent = (const float*)d_in[1];
    const float* bias = (const float*)d_in[2];
    const float* wgs = (const float*)d_in[3];
    const float* wus = (const float*)d_in[4];
    const float* wds = (const float*)d_in[5];
    const float* wg = (const float*)d_in[6];
    const float* wu = (const float*)d_in[7];
    const float* wd = (const float*)d_in[8];
    float* out = (float*)d_out;
    char* ws = (char*)d_ws;

    size_t off_wtgs = 0;
    size_t off_wtus = off_wtgs + (size_t)HDIM * ISH * 2;
    size_t off_wtds = off_wtus + (size_t)HDIM * ISH * 2;
    size_t off_wtg = off_wtds + (size_t)ISH * HDIM * 2;
    size_t off_wtu = off_wtg + (size_t)NEXP * HDIM * IDIM * 2;
    size_t off_wtd = off_wtu + (size_t)NEXP * HDIM * IDIM * 2;
    size_t off_xbf = off_wtd + (size_t)NEXP * IDIM * HDIM * 2;
    size_t off_hsh = off_xbf + (size_t)TOKENS * HDIM * 2;
    size_t off_hrt = off_hsh + (size_t)TOKENS * ISH * 2;
    size_t off_meta = off_hrt + (size_t)2 * TOKENS * IDIM * 2;
    size_t need = off_meta + (1 << 20);
    if (ws_size < need) return;  // main path verified present in round 2

    u16* Wt_gs = (u16*)(ws + off_wtgs);
    u16* Wt_us = (u16*)(ws + off_wtus);
    u16* Wt_ds = (u16*)(ws + off_wtds);
    u16* Wt_g = (u16*)(ws + off_wtg);
    u16* Wt_u = (u16*)(ws + off_wtu);
    u16* Wt_d = (u16*)(ws + off_wtd);
    u16* x_bf = (u16*)(ws + off_xbf);
    u16* h_sh = (u16*)(ws + off_hsh);
    u16* h_rt = (u16*)(ws + off_hrt);
    // rd (67 MB, f32 [8192][2048]) at off_wtg: overlaps routed gate/up weights
    // only; their last reader (merged gateup) completes before gemm_down writes
    // rd. Down reads Wt_ds/Wt_d (outside overlap) + h buffers. conv_all rewrites
    // the weights at the start of the next captured iteration.
    float* rd = (float*)(ws + off_wtg);
    int* counts = (int*)(ws + off_meta);
    int* offsets = counts + 16;
    int* itemsGU = offsets + 16;
    int* itemsD = itemsGU + GUITEMS;
    int* tok2slot = itemsD + DITEMS;
    int* top_e = tok2slot + 2 * TOKENS;
    float* top_w = (float*)(top_e + 2 * TOKENS);
    int* list_tok = (int*)(top_w + 2 * TOKENS);

    route_kernel<<<TOKENS / 4, 256, 0, stream>>>(x, cent, bias, x_bf, top_e, top_w);
    build_kernel<<<1, 1024, 0, stream>>>(top_e, top_w, counts, offsets, itemsGU, itemsD,
                                         list_tok, tok2slot);
    conv_all_kernel<<<6912, 256, 0, stream>>>(wgs, wus, wds, wg, wu, wd, Wt_gs, Wt_us,
                                              Wt_ds, Wt_g, Wt_u, Wt_d);
    gemm_gateup<<<GUITEMS, 256, 0, stream>>>(x_bf, Wt_gs, Wt_us, Wt_g, Wt_u, h_sh, h_rt,
                                             counts, offsets, list_tok, itemsGU);
    gemm_down<<<DITEMS, 256, 0, stream>>>(h_sh, h_rt, Wt_ds, Wt_d, out, rd, counts,
                                          offsets, itemsD);
    combine_kernel<<<TOKENS, 256, 0, stream>>>(out, rd, tok2slot, top_w);
}

// Round 10
// 859.063 us; speedup vs baseline: 1.0798x; 1.0078x over previous
//
#include <hip/hip_runtime.h>
#include <hip/hip_bf16.h>

typedef unsigned short u16;
typedef unsigned int u32;
typedef unsigned long long u64;
typedef __attribute__((ext_vector_type(8))) short short8;
typedef __attribute__((ext_vector_type(4))) float f32x4;

#define TOKENS 4096
#define HDIM 2048
#define NEXP 16
#define IDIM 1024
#define ISH 2048
#define NCHUNK 128  // 8192 route entries / 64 lanes

// merged GEMM work lists (16-item supertiles; counts divisible by 128)
#define GUITEMS 2304  // 144 supertiles = 8 XCD groups x 18
#define DITEMS 2048   // 128 supertiles = 8 x 16

#define AS1(p) ((const __attribute__((address_space(1))) u32*)(p))
#define AS3(p) ((__attribute__((address_space(3))) u32*)(p))

__device__ __forceinline__ u16 f2b(float f) {
    u32 u = __float_as_uint(f);
    u32 r = u + 0x7fffu + ((u >> 16) & 1u);
    return (u16)(r >> 16);
}

// supertile round-robin: supertile s -> XCD s%8 (keeps 16-item supertile on one
// XCD for L2 reuse; spreads shared/routed/dead supertiles evenly across XCDs)
__device__ __forceinline__ int item_index(int bid) {
    int x = bid & 7, j = bid >> 3;
    return ((x + 8 * (j >> 4)) << 4) | (j & 15);
}

// ---------------- routing: 1 wave per token; ALSO emits x_bf (fused convert) --
__global__ __launch_bounds__(256) void route_kernel(const float* __restrict__ x,
                                                    const float* __restrict__ cent,
                                                    const float* __restrict__ bias,
                                                    u16* __restrict__ xb,
                                                    int* __restrict__ top_e,
                                                    float* __restrict__ top_w) {
    __shared__ alignas(16) float cs[8 * 2048];  // 64KB: 8 experts per phase
    int lane = threadIdx.x & 63;
    int wv = threadIdx.x >> 6;
    int t = blockIdx.x * 4 + wv;
    const float4* xp4 = (const float4*)(x + (size_t)t * HDIM);
    float4 xr[8];
#pragma unroll
    for (int i = 0; i < 8; i++) xr[i] = xp4[lane + 64 * i];
    // fused convert: store this token row as bf16 (row already in registers)
    u16* xbp = xb + (size_t)t * HDIM;
#pragma unroll
    for (int i = 0; i < 8; i++) {
        u32 lo = (u32)f2b(xr[i].x) | ((u32)f2b(xr[i].y) << 16);
        u32 hi = (u32)f2b(xr[i].z) | ((u32)f2b(xr[i].w) << 16);
        uint2 o = make_uint2(lo, hi);
        *(uint2*)(xbp + (size_t)(lane + 64 * i) * 4) = o;
    }
    float aff[16];
#pragma unroll
    for (int ph = 0; ph < 2; ph++) {
        if (ph) __syncthreads();
        const float* sbase = cent + (size_t)(ph * 8 + wv * 2) * HDIM;
        float* dbase = cs + (size_t)wv * 2 * HDIM;
#pragma unroll
        for (int i = 0; i < 16; i++) {
            __builtin_amdgcn_global_load_lds(AS1(sbase + i * 256 + lane * 4),
                                             AS3(dbase + i * 256), 16, 0, 0);
        }
        __syncthreads();
#pragma unroll
        for (int e = 0; e < 8; e++) {
            const float4* cp = (const float4*)cs + (size_t)e * 512;
            float s = 0.f;
#pragma unroll
            for (int i = 0; i < 8; i++) {
                float4 cv = cp[lane + 64 * i];
                s += xr[i].x * cv.x;
                s += xr[i].y * cv.y;
                s += xr[i].z * cv.z;
                s += xr[i].w * cv.w;
            }
#pragma unroll
            for (int off = 32; off > 0; off >>= 1) s += __shfl_xor(s, off, 64);
            aff[ph * 8 + e] = 1.f / (1.f + expf(-s));
        }
    }
    float b0 = -1e30f, b1 = -1e30f, a0 = 0.f, a1 = 0.f;
    int e0 = -1, e1 = -1;
#pragma unroll
    for (int e = 0; e < 16; e++) {
        float v = aff[e] + bias[e];
        if (v > b0) {
            b1 = b0; e1 = e0; a1 = a0;
            b0 = v; e0 = e; a0 = aff[e];
        } else if (v > b1) {
            b1 = v; e1 = e; a1 = aff[e];
        }
    }
    float inv = 1.f / (a0 + a1 + 1e-9f);
    if (lane == 0) {
        top_e[2 * t] = e0; top_w[2 * t] = a0 * inv;
        top_e[2 * t + 1] = e1; top_w[2 * t + 1] = a1 * inv;
    }
}

// ---------------- build: histogram + scan + work-item lists + scatter ----------
// Items: (routed<<28)|(e<<20)|(mtile<<8)|yblock, -1 = dead.
__global__ __launch_bounds__(1024) void build_kernel(
    const int* __restrict__ top_e, const float* __restrict__ top_w,
    int* __restrict__ counts, int* __restrict__ offsets, int* __restrict__ itemsGU,
    int* __restrict__ itemsD, int* __restrict__ list_tok, int* __restrict__ tok2slot) {
    __shared__ int cnt[NCHUNK][16];
    __shared__ int offs_s[16];
    __shared__ int totals[16];
    __shared__ int guPref[16], dPref[16];
    int tid = threadIdx.x;
    int lane = tid & 63, wv = tid >> 6;  // 16 waves
    for (int i = tid; i < GUITEMS; i += 1024) itemsGU[i] = -1;
    for (int i = tid; i < DITEMS; i += 1024) itemsD[i] = -1;
    for (int c = wv; c < NCHUNK; c += 16) {
        int v = top_e[c * 64 + lane];
#pragma unroll
        for (int e = 0; e < 16; e++) {
            u64 m = __ballot(v == e);
            if (lane == 0) cnt[c][e] = (int)__popcll(m);
        }
    }
    __syncthreads();
    if (tid < 16) {
        int s = 0;
        for (int c = 0; c < NCHUNK; c++) s += cnt[c][tid];
        totals[tid] = s;
        counts[tid] = s;
    }
    __syncthreads();
    if (tid == 0) {
        int r = 0, g = 0, d = 0;
        for (int e = 0; e < 16; e++) {
            offs_s[e] = r;
            offsets[e] = r;
            r += totals[e];
            guPref[e] = g;
            g += ((totals[e] + 127) >> 7) * 16;
            dPref[e] = d;
            d += ((totals[e] + 255) >> 8) * 32;
        }
    }
    // shared-GEMM items (supertiles of 16 consecutive items)
    {
        int i = tid;  // 1024 items: supertile (4m x 4y)
        int g = i >> 4, s = i & 15;
        int y0 = (g >> 3) << 2, m0 = (g & 7) << 2;
        itemsGU[i] = ((m0 + (s >> 2)) << 8) | (y0 + (s & 3));
    }
    if (tid < 512) {
        int i = tid;
        int g = i >> 4, s = i & 15;
        int y0 = (g >> 2) << 2, m0 = (g & 3) << 2;
        itemsD[i] = ((m0 + (s >> 2)) << 8) | (y0 + (s & 3));
    }
    __syncthreads();
    // routed items + per-chunk bases (16 threads)
    if (tid < 16) {
        int e = tid;
        int tA = (totals[e] + 127) >> 7;
        int p = 1024 + guPref[e];
        for (int y0 = 0; y0 < 16; y0 += 4)
            for (int m = 0; m < tA; m++)
                for (int dy = 0; dy < 4; dy++)
                    itemsGU[p++] = (1 << 28) | (e << 20) | (m << 8) | (y0 + dy);
        int tB = (totals[e] + 255) >> 8;
        p = 512 + dPref[e];
        for (int y0 = 0; y0 < 32; y0 += 4)
            for (int m = 0; m < tB; m++)
                for (int dy = 0; dy < 4; dy++)
                    itemsD[p++] = (1 << 28) | (e << 20) | (m << 8) | (y0 + dy);
        int r = offs_s[e];
        for (int c = 0; c < NCHUNK; c++) {
            int v = cnt[c][e];
            cnt[c][e] = r;
            r += v;
        }
    }
    __syncthreads();
    for (int c = wv; c < NCHUNK; c += 16) {
        int i = c * 64 + lane;
        int v = top_e[i];
        int rank = 0;
#pragma unroll
        for (int e = 0; e < 16; e++) {
            u64 m = __ballot(v == e);
            if (v == e) rank = (int)__popcll(m & ((1ull << lane) - 1ull));
        }
        int slot = cnt[c][v] + rank;
        list_tok[slot] = i >> 1;
        tok2slot[i] = slot;
    }
}

// ================= MAIN PATH =================
// ALL weight conversions in ONE dispatch: flat grid of (matrix, nt, kc) units.
// fp32 W[K][N] -> bf16 tiled [N/64][K/32][64][32] with XOR swizzle.
__global__ __launch_bounds__(256) void conv_all_kernel(
    const float* __restrict__ wgs, const float* __restrict__ wus,
    const float* __restrict__ wds, const float* __restrict__ wg,
    const float* __restrict__ wu, const float* __restrict__ wd, u16* __restrict__ Wt_gs,
    u16* __restrict__ Wt_us, u16* __restrict__ Wt_ds, u16* __restrict__ Wt_g,
    u16* __restrict__ Wt_u, u16* __restrict__ Wt_d) {
    int id = blockIdx.x;
    const float* Wm;
    u16* Wtm;
    int K, N, nt, kc;
    if (id < 768) {  // shared: 3 x 256 units, K=2048 N=2048
        K = 2048; N = 2048;
        int seg = id >> 8, r = id & 255;
        nt = r & 31; kc = r >> 5;
        if (seg == 0) { Wm = wgs; Wtm = Wt_gs; }
        else if (seg == 1) { Wm = wus; Wtm = Wt_us; }
        else { Wm = wds; Wtm = Wt_ds; }
    } else if (id < 4864) {  // wg/wu: 2 x 16e x 128 units, K=2048 N=1024
        K = 2048; N = 1024;
        int r = id - 768;
        int m = r >> 11;
        r &= 2047;
        int e = r >> 7;
        r &= 127;
        nt = r & 15; kc = r >> 4;
        size_t off = (size_t)e * 2048 * 1024;
        if (m == 0) { Wm = wg + off; Wtm = Wt_g + off; }
        else { Wm = wu + off; Wtm = Wt_u + off; }
    } else {  // wd: 16e x 128 units, K=1024 N=2048
        K = 1024; N = 2048;
        int r = id - 4864;
        int e = r >> 7;
        r &= 127;
        nt = r & 31; kc = r >> 5;
        size_t off = (size_t)e * 1024 * 2048;
        Wm = wd + off; Wtm = Wt_d + off;
    }
    int ksB = K >> 5;
    __shared__ u16 Ls[64 * 40];
    int t = threadIdx.x;
    int kr = t >> 3, ng = t & 7;
    int nn = t >> 2, seg2 = t & 3;
    int g = seg2 ^ ((nn >> 2) & 3);
#pragma unroll
    for (int s = 0; s < 8; s++) {
        int kb = kc * 256 + s * 32;
        const float* src = Wm + (size_t)(kb + kr) * N + nt * 64 + ng * 8;
        float4 f0 = *(const float4*)src;
        float4 f1 = *(const float4*)(src + 4);
        __syncthreads();
        const float* p0 = (const float*)&f0;
        const float* p1 = (const float*)&f1;
#pragma unroll
        for (int l = 0; l < 4; l++) Ls[(8 * ng + l) * 40 + kr] = f2b(p0[l]);
#pragma unroll
        for (int l = 0; l < 4; l++) Ls[(8 * ng + 4 + l) * 40 + kr] = f2b(p1[l]);
        __syncthreads();
        const u16* lp = &Ls[nn * 40 + g * 8];
        u32 w0 = (u32)lp[0] | ((u32)lp[1] << 16);
        u32 w1 = (u32)lp[2] | ((u32)lp[3] << 16);
        u32 w2 = (u32)lp[4] | ((u32)lp[5] << 16);
        u32 w3 = (u32)lp[6] | ((u32)lp[7] << 16);
        uint4 o = make_uint4(w0, w1, w2, w3);
        *(uint4*)(Wtm + (size_t)(nt * ksB + (kb >> 5)) * 2048 + t * 8) = o;
    }
}

// merged fused gate+up (shared + routed): M-tile 128, N-tile 64, BK 64.
// 8-wave (512-thread) blocks: waves 0-3 compute gate, waves 4-7 compute up.
// Per-wave acc = 32 AGPR (vs 64 fused) -> target <=128 regs/wave = 4 waves/SIMD
// (16 waves/CU, vs 12 with the 4-wave dual-acc version; r5 showed occupancy is
// first-order here). Up waves hand u to gate waves via LDS at epilogue.
__global__ __launch_bounds__(512, 4) void gemm_gateup(
    const u16* __restrict__ A, const u16* __restrict__ BgS, const u16* __restrict__ BuS,
    const u16* __restrict__ BgR, const u16* __restrict__ BuR, u16* __restrict__ hS,
    u16* __restrict__ hR, const int* __restrict__ counts, const int* __restrict__ offsets,
    const int* __restrict__ list_tok, const int* __restrict__ items) {
    int it = items[item_index(blockIdx.x)];
    if (it < 0) return;
    int routed = (it >> 28) & 1;
    int e = (it >> 20) & 15;
    int m0 = ((it >> 8) & 4095) * 128;
    int yb = it & 255;
    int cnt, base, Nout;
    const u16 *Bg, *Bu;
    u16* hout;
    if (routed) {
        cnt = counts[e];
        base = offsets[e];
        Nout = IDIM;
        size_t off = (size_t)e * HDIM * IDIM;
        Bg = BgR + off;
        Bu = BuR + off;
        hout = hR;
    } else {
        cnt = TOKENS;
        base = 0;
        Nout = ISH;
        Bg = BgS;
        Bu = BuS;
        hout = hS;
    }
    const int nk = HDIM >> 6;  // BK=64 steps
    __shared__ alignas(16) u16 As[128 * 64];   // chunk c at c*4096 (128r x 32k)
    __shared__ alignas(16) u16 Bgs[64 * 64];   // chunk c at c*2048
    __shared__ alignas(16) u16 Bus[64 * 64];
    __shared__ alignas(16) float us[128 * 64];  // up -> gate exchange (epilogue)
    int tid = threadIdx.x;
    int lane = tid & 63, wv = tid >> 6;  // 8 waves
    int wl = wv & 3, mat = wv >> 2;      // mat: 0=gate, 1=up
    int quad = lane >> 4, mr = lane & 15;
    int n0 = yb * 64;
    int gk = (tid & 3) ^ ((tid >> 4) & 3);
    int mg0 = min(m0 + (tid >> 2), cnt - 1);
    size_t sr0 = routed ? (size_t)list_tok[base + mg0] : (size_t)mg0;
    const u16* ap0 = A + sr0 * HDIM + gk * 8;  // thread stages row tid>>2 (0..127)
    size_t bstr = (size_t)(HDIM >> 5) * 2048;
    // B staging: waves 0-3 stage Bg, waves 4-7 stage Bu (virtual tid = tid&255)
    const u16* bsrc = (mat ? Bu : Bg) + (size_t)yb * bstr + (size_t)(tid & 255) * 8;
    u16* bdstW = (mat ? Bus : Bgs) + wl * 512;
    u16* adstW = As + wv * 512;  // wave w stages A rows 16w..16w+15
    const u16* bbuf = mat ? Bus : Bgs;  // compute reads own matrix
    int xq = quad ^ ((mr >> 2) & 3);
    f32x4 acc[2][4];
#pragma unroll
    for (int i = 0; i < 2; i++)
#pragma unroll
        for (int j = 0; j < 4; j++) acc[i][j] = (f32x4)0.f;

    for (int ks = 0; ks < nk; ks++) {
        __syncthreads();
        __builtin_amdgcn_global_load_lds(AS1(ap0), AS3(adstW), 16, 0, 0);
        __builtin_amdgcn_global_load_lds(AS1(ap0 + 32), AS3(adstW + 4096), 16, 0, 0);
        __builtin_amdgcn_global_load_lds(AS1(bsrc), AS3(bdstW), 16, 0, 0);
        __builtin_amdgcn_global_load_lds(AS1(bsrc + 2048), AS3(bdstW + 2048), 16, 0, 0);
        ap0 += 64; bsrc += 4096;
        __syncthreads();
#pragma unroll
        for (int c = 0; c < 2; c++) {
            short8 a0 = *(const short8*)(As + c * 4096 + ((32 * wl + mr) * 4 + xq) * 8);
            short8 a1 = *(const short8*)(As + c * 4096 + ((32 * wl + 16 + mr) * 4 + xq) * 8);
#pragma unroll
            for (int j = 0; j < 4; j++) {
                short8 b = *(const short8*)(bbuf + c * 2048 + (64 * j + mr * 4 + xq) * 8);
                acc[0][j] = __builtin_amdgcn_mfma_f32_16x16x32_bf16(a0, b, acc[0][j], 0, 0, 0);
                acc[1][j] = __builtin_amdgcn_mfma_f32_16x16x32_bf16(a1, b, acc[1][j], 0, 0, 0);
            }
        }
    }
    // epilogue: up waves publish u; gate waves combine h = silu(g)*u and store.
    __syncthreads();
    if (mat == 1) {
#pragma unroll
        for (int i = 0; i < 2; i++)
#pragma unroll
            for (int j = 0; j < 4; j++)
#pragma unroll
                for (int r = 0; r < 4; r++) {
                    int row = 32 * wl + 16 * i + quad * 4 + r;
                    us[row * 64 + 16 * j + mr] = acc[i][j][r];
                }
    }
    __syncthreads();
    if (mat == 0) {
#pragma unroll
        for (int i = 0; i < 2; i++)
#pragma unroll
            for (int j = 0; j < 4; j++)
#pragma unroll
                for (int r = 0; r < 4; r++) {
                    int row = 32 * wl + 16 * i + quad * 4 + r;
                    int m = m0 + row;
                    if (m < cnt) {
                        float gv = acc[i][j][r];
                        float uv = us[row * 64 + 16 * j + mr];
                        float h = gv / (1.f + expf(-gv)) * uv;
                        int n = n0 + 16 * j + mr;
                        hout[(size_t)(base + m) * Nout + n] = f2b(h);
                    }
                }
    }
}

// merged down GEMM (shared + routed): M-tile 256, N-tile 64, BK 64.
__global__ __launch_bounds__(256) void gemm_down(
    const u16* __restrict__ hS, const u16* __restrict__ hR, const u16* __restrict__ BdS,
    const u16* __restrict__ BdR, float* __restrict__ out, float* __restrict__ rd,
    const int* __restrict__ counts, const int* __restrict__ offsets,
    const int* __restrict__ items) {
    int it = items[item_index(blockIdx.x)];
    if (it < 0) return;
    int routed = (it >> 28) & 1;
    int e = (it >> 20) & 15;
    int m0 = ((it >> 8) & 4095) * 256;
    int yb = it & 255;
    int cnt, base, Kd;
    const u16 *A, *B;
    float* outp;
    if (routed) {
        cnt = counts[e];
        base = offsets[e];
        Kd = IDIM;
        A = hR;
        B = BdR + (size_t)e * IDIM * HDIM;
        outp = rd;
    } else {
        cnt = TOKENS;
        base = 0;
        Kd = ISH;
        A = hS;
        B = BdS;
        outp = out;
    }
    int nk = Kd >> 6;  // BK=64
    __shared__ alignas(16) u16 As[256 * 64];
    __shared__ alignas(16) u16 Bs[64 * 64];
    int tid = threadIdx.x;
    int lane = tid & 63, wv = tid >> 6;
    int quad = lane >> 4, mr = lane & 15;
    int n0 = yb * 64;
    int gk = (tid & 3) ^ ((tid >> 4) & 3);
    const u16* ap0;
    const u16* ap1;
    const u16* ap2;
    const u16* ap3;
    {
        int mg0 = base + min(m0 + 0 * 64 + (tid >> 2), cnt - 1);
        int mg1 = base + min(m0 + 1 * 64 + (tid >> 2), cnt - 1);
        int mg2 = base + min(m0 + 2 * 64 + (tid >> 2), cnt - 1);
        int mg3 = base + min(m0 + 3 * 64 + (tid >> 2), cnt - 1);
        ap0 = A + (size_t)mg0 * Kd + gk * 8;
        ap1 = A + (size_t)mg1 * Kd + gk * 8;
        ap2 = A + (size_t)mg2 * Kd + gk * 8;
        ap3 = A + (size_t)mg3 * Kd + gk * 8;
    }
    size_t bstr = (size_t)(Kd >> 5) * 2048;
    const u16* bp = B + (size_t)yb * bstr + tid * 8;
    int xq = quad ^ ((mr >> 2) & 3);
    f32x4 acc[4][4];
#pragma unroll
    for (int i = 0; i < 4; i++)
#pragma unroll
        for (int j = 0; j < 4; j++) acc[i][j] = (f32x4)0.f;

    for (int ks = 0; ks < nk; ks++) {
        __syncthreads();
        __builtin_amdgcn_global_load_lds(AS1(ap0), AS3(As + 0 + wv * 512), 16, 0, 0);
        __builtin_amdgcn_global_load_lds(AS1(ap0 + 32), AS3(As + 8192 + wv * 512), 16, 0, 0);
        __builtin_amdgcn_global_load_lds(AS1(ap1), AS3(As + 2048 + wv * 512), 16, 0, 0);
        __builtin_amdgcn_global_load_lds(AS1(ap1 + 32), AS3(As + 10240 + wv * 512), 16, 0, 0);
        __builtin_amdgcn_global_load_lds(AS1(ap2), AS3(As + 4096 + wv * 512), 16, 0, 0);
        __builtin_amdgcn_global_load_lds(AS1(ap2 + 32), AS3(As + 12288 + wv * 512), 16, 0, 0);
        __builtin_amdgcn_global_load_lds(AS1(ap3), AS3(As + 6144 + wv * 512), 16, 0, 0);
        __builtin_amdgcn_global_load_lds(AS1(ap3 + 32), AS3(As + 14336 + wv * 512), 16, 0, 0);
        __builtin_amdgcn_global_load_lds(AS1(bp), AS3(Bs + wv * 512), 16, 0, 0);
        __builtin_amdgcn_global_load_lds(AS1(bp + 2048), AS3(Bs + 2048 + wv * 512), 16, 0, 0);
        ap0 += 64; ap1 += 64; ap2 += 64; ap3 += 64; bp += 4096;
        __syncthreads();
#pragma unroll
        for (int c = 0; c < 2; c++) {
            short8 a0 = *(const short8*)(As + c * 8192 + ((64 * wv + 0 + mr) * 4 + xq) * 8);
            short8 a1 = *(const short8*)(As + c * 8192 + ((64 * wv + 16 + mr) * 4 + xq) * 8);
            short8 a2 = *(const short8*)(As + c * 8192 + ((64 * wv + 32 + mr) * 4 + xq) * 8);
            short8 a3 = *(const short8*)(As + c * 8192 + ((64 * wv + 48 + mr) * 4 + xq) * 8);
#pragma unroll
            for (int j = 0; j < 4; j++) {
                short8 b = *(const short8*)(Bs + c * 2048 + (64 * j + mr * 4 + xq) * 8);
                acc[0][j] = __builtin_amdgcn_mfma_f32_16x16x32_bf16(a0, b, acc[0][j], 0, 0, 0);
                acc[1][j] = __builtin_amdgcn_mfma_f32_16x16x32_bf16(a1, b, acc[1][j], 0, 0, 0);
                acc[2][j] = __builtin_amdgcn_mfma_f32_16x16x32_bf16(a2, b, acc[2][j], 0, 0, 0);
                acc[3][j] = __builtin_amdgcn_mfma_f32_16x16x32_bf16(a3, b, acc[3][j], 0, 0, 0);
            }
        }
    }

#pragma unroll
    for (int i = 0; i < 4; i++)
#pragma unroll
        for (int j = 0; j < 4; j++)
#pragma unroll
            for (int r = 0; r < 4; r++) {
                int m = m0 + 64 * wv + 16 * i + quad * 4 + r;
                if (m >= cnt) continue;
                int n = n0 + 16 * j + mr;
                float v = acc[i][j][r];
                if (routed) {
                    outp[(size_t)(base + m) * HDIM + n] = v;  // per-slot, no atomics
                } else {
                    outp[(size_t)m * HDIM + n] = 0.1f * v;
                }
            }
}

// ---------------- combine: out[t] += w0*rd[slot0] + w1*rd[slot1] ----------------
__global__ __launch_bounds__(256) void combine_kernel(float* __restrict__ out,
                                                      const float* __restrict__ rd,
                                                      const int* __restrict__ tok2slot,
                                                      const float* __restrict__ top_w) {
    int t = blockIdx.x;
    int s0 = tok2slot[2 * t], s1 = tok2slot[2 * t + 1];
    float w0 = top_w[2 * t], w1 = top_w[2 * t + 1];
    const float4* r0 = (const float4*)(rd + (size_t)s0 * HDIM);
    const float4* r1 = (const float4*)(rd + (size_t)s1 * HDIM);
    float4* op = (float4*)(out + (size_t)t * HDIM);
#pragma unroll
    for (int k = 0; k < 2; k++) {
        int c = threadIdx.x + k * 256;
        float4 o = op[c];
        float4 a = r0[c];
        float4 b = r1[c];
        o.x += w0 * a.x + w1 * b.x;
        o.y += w0 * a.y + w1 * b.y;
        o.z += w0 * a.z + w1 * b.z;
        o.w += w0 * a.w + w1 * b.w;
        op[c] = o;
    }
}

extern "C" void kernel_launch(void* const* d_in, const int* in_sizes, int n_in,
                              void* d_out, int out_size, void* d_ws, size_t ws_size,
                              hipStream_t stream) {
    const float* x = (const float*)d_in[0];
    const float* cent = (const float*)d_in[1];
    const float* bias = (const float*)d_in[2];
    const float* wgs = (const float*)d_in[3];
    const float* wus = (const float*)d_in[4];
    const float* wds = (const float*)d_in[5];
    const float* wg = (const float*)d_in[6];
    const float* wu = (const float*)d_in[7];
    const float* wd = (const float*)d_in[8];
    float* out = (float*)d_out;
    char* ws = (char*)d_ws;

    size_t off_wtgs = 0;
    size_t off_wtus = off_wtgs + (size_t)HDIM * ISH * 2;
    size_t off_wtds = off_wtus + (size_t)HDIM * ISH * 2;
    size_t off_wtg = off_wtds + (size_t)ISH * HDIM * 2;
    size_t off_wtu = off_wtg + (size_t)NEXP * HDIM * IDIM * 2;
    size_t off_wtd = off_wtu + (size_t)NEXP * HDIM * IDIM * 2;
    size_t off_xbf = off_wtd + (size_t)NEXP * IDIM * HDIM * 2;
    size_t off_hsh = off_xbf + (size_t)TOKENS * HDIM * 2;
    size_t off_hrt = off_hsh + (size_t)TOKENS * ISH * 2;
    size_t off_meta = off_hrt + (size_t)2 * TOKENS * IDIM * 2;
    size_t need = off_meta + (1 << 20);
    if (ws_size < need) return;  // main path verified present in round 2

    u16* Wt_gs = (u16*)(ws + off_wtgs);
    u16* Wt_us = (u16*)(ws + off_wtus);
    u16* Wt_ds = (u16*)(ws + off_wtds);
    u16* Wt_g = (u16*)(ws + off_wtg);
    u16* Wt_u = (u16*)(ws + off_wtu);
    u16* Wt_d = (u16*)(ws + off_wtd);
    u16* x_bf = (u16*)(ws + off_xbf);
    u16* h_sh = (u16*)(ws + off_hsh);
    u16* h_rt = (u16*)(ws + off_hrt);
    // rd (67 MB, f32 [8192][2048]) at off_wtg: overlaps routed gate/up weights
    // only; their last reader (merged gateup) completes before gemm_down writes
    // rd. Down reads Wt_ds/Wt_d (outside overlap) + h buffers. conv_all rewrites
    // the weights at the start of the next captured iteration.
    float* rd = (float*)(ws + off_wtg);
    int* counts = (int*)(ws + off_meta);
    int* offsets = counts + 16;
    int* itemsGU = offsets + 16;
    int* itemsD = itemsGU + GUITEMS;
    int* tok2slot = itemsD + DITEMS;
    int* top_e = tok2slot + 2 * TOKENS;
    float* top_w = (float*)(top_e + 2 * TOKENS);
    int* list_tok = (int*)(top_w + 2 * TOKENS);

    route_kernel<<<TOKENS / 4, 256, 0, stream>>>(x, cent, bias, x_bf, top_e, top_w);
    build_kernel<<<1, 1024, 0, stream>>>(top_e, top_w, counts, offsets, itemsGU, itemsD,
                                         list_tok, tok2slot);
    conv_all_kernel<<<6912, 256, 0, stream>>>(wgs, wus, wds, wg, wu, wd, Wt_gs, Wt_us,
                                              Wt_ds, Wt_g, Wt_u, Wt_d);
    gemm_gateup<<<GUITEMS, 512, 0, stream>>>(x_bf, Wt_gs, Wt_us, Wt_g, Wt_u, h_sh, h_rt,
                                             counts, offsets, list_tok, itemsGU);
    gemm_down<<<DITEMS, 256, 0, stream>>>(h_sh, h_rt, Wt_ds, Wt_d, out, rd, counts,
                                          offsets, itemsD);
    combine_kernel<<<TOKENS, 256, 0, stream>>>(out, rd, tok2slot, top_w);
}

// Round 11
// 835.339 us; speedup vs baseline: 1.1105x; 1.0284x over previous
//
#include <hip/hip_runtime.h>
#include <hip/hip_bf16.h>

typedef unsigned short u16;
typedef unsigned int u32;
typedef unsigned long long u64;
typedef __attribute__((ext_vector_type(8))) short short8;
typedef __attribute__((ext_vector_type(4))) float f32x4;

#define TOKENS 4096
#define HDIM 2048
#define NEXP 16
#define IDIM 1024
#define ISH 2048
#define NCHUNK 128  // 8192 route entries / 64 lanes

// merged GEMM work lists (16-item supertiles)
#define GUITEMS 1152  // 72 supertiles = 8 XCD groups x 9 (y-panels of 128)
#define DITEMS 2048   // 128 supertiles = 8 x 16

#define AS1(p) ((const __attribute__((address_space(1))) u32*)(p))
#define AS3(p) ((__attribute__((address_space(3))) u32*)(p))

__device__ __forceinline__ u16 f2b(float f) {
    u32 u = __float_as_uint(f);
    u32 r = u + 0x7fffu + ((u >> 16) & 1u);
    return (u16)(r >> 16);
}

// supertile round-robin: supertile s -> XCD s%8 (keeps a 16-item supertile on
// one XCD for L2 reuse; spreads shared/routed/dead supertiles evenly)
__device__ __forceinline__ int item_index(int bid) {
    int x = bid & 7, j = bid >> 3;
    return ((x + 8 * (j >> 4)) << 4) | (j & 15);
}

// ---------------- routing: 1 wave per token; ALSO emits x_bf (fused convert) --
__global__ __launch_bounds__(256) void route_kernel(const float* __restrict__ x,
                                                    const float* __restrict__ cent,
                                                    const float* __restrict__ bias,
                                                    u16* __restrict__ xb,
                                                    int* __restrict__ top_e,
                                                    float* __restrict__ top_w) {
    __shared__ alignas(16) float cs[8 * 2048];  // 64KB: 8 experts per phase
    int lane = threadIdx.x & 63;
    int wv = threadIdx.x >> 6;
    int t = blockIdx.x * 4 + wv;
    const float4* xp4 = (const float4*)(x + (size_t)t * HDIM);
    float4 xr[8];
#pragma unroll
    for (int i = 0; i < 8; i++) xr[i] = xp4[lane + 64 * i];
    u16* xbp = xb + (size_t)t * HDIM;
#pragma unroll
    for (int i = 0; i < 8; i++) {
        u32 lo = (u32)f2b(xr[i].x) | ((u32)f2b(xr[i].y) << 16);
        u32 hi = (u32)f2b(xr[i].z) | ((u32)f2b(xr[i].w) << 16);
        uint2 o = make_uint2(lo, hi);
        *(uint2*)(xbp + (size_t)(lane + 64 * i) * 4) = o;
    }
    float aff[16];
#pragma unroll
    for (int ph = 0; ph < 2; ph++) {
        if (ph) __syncthreads();
        const float* sbase = cent + (size_t)(ph * 8 + wv * 2) * HDIM;
        float* dbase = cs + (size_t)wv * 2 * HDIM;
#pragma unroll
        for (int i = 0; i < 16; i++) {
            __builtin_amdgcn_global_load_lds(AS1(sbase + i * 256 + lane * 4),
                                             AS3(dbase + i * 256), 16, 0, 0);
        }
        __syncthreads();
#pragma unroll
        for (int e = 0; e < 8; e++) {
            const float4* cp = (const float4*)cs + (size_t)e * 512;
            float s = 0.f;
#pragma unroll
            for (int i = 0; i < 8; i++) {
                float4 cv = cp[lane + 64 * i];
                s += xr[i].x * cv.x;
                s += xr[i].y * cv.y;
                s += xr[i].z * cv.z;
                s += xr[i].w * cv.w;
            }
#pragma unroll
            for (int off = 32; off > 0; off >>= 1) s += __shfl_xor(s, off, 64);
            aff[ph * 8 + e] = 1.f / (1.f + expf(-s));
        }
    }
    float b0 = -1e30f, b1 = -1e30f, a0 = 0.f, a1 = 0.f;
    int e0 = -1, e1 = -1;
#pragma unroll
    for (int e = 0; e < 16; e++) {
        float v = aff[e] + bias[e];
        if (v > b0) {
            b1 = b0; e1 = e0; a1 = a0;
            b0 = v; e0 = e; a0 = aff[e];
        } else if (v > b1) {
            b1 = v; e1 = e; a1 = aff[e];
        }
    }
    float inv = 1.f / (a0 + a1 + 1e-9f);
    if (lane == 0) {
        top_e[2 * t] = e0; top_w[2 * t] = a0 * inv;
        top_e[2 * t + 1] = e1; top_w[2 * t + 1] = a1 * inv;
    }
}

// ---------------- build: histogram + scan + work-item lists + scatter ----------
// GU items (y-panels of 128): (routed<<28)|(e<<20)|(mtile<<8)|y128, -1 = dead.
// D items (y-panels of 64) unchanged.
__global__ __launch_bounds__(1024) void build_kernel(
    const int* __restrict__ top_e, const float* __restrict__ top_w,
    int* __restrict__ counts, int* __restrict__ offsets, int* __restrict__ itemsGU,
    int* __restrict__ itemsD, int* __restrict__ list_tok, int* __restrict__ tok2slot) {
    __shared__ int cnt[NCHUNK][16];
    __shared__ int offs_s[16];
    __shared__ int totals[16];
    __shared__ int guPref[16], dPref[16];
    int tid = threadIdx.x;
    int lane = tid & 63, wv = tid >> 6;  // 16 waves
    for (int i = tid; i < GUITEMS; i += 1024) itemsGU[i] = -1;
    for (int i = tid; i < DITEMS; i += 1024) itemsD[i] = -1;
    for (int c = wv; c < NCHUNK; c += 16) {
        int v = top_e[c * 64 + lane];
#pragma unroll
        for (int e = 0; e < 16; e++) {
            u64 m = __ballot(v == e);
            if (lane == 0) cnt[c][e] = (int)__popcll(m);
        }
    }
    __syncthreads();
    if (tid < 16) {
        int s = 0;
        for (int c = 0; c < NCHUNK; c++) s += cnt[c][tid];
        totals[tid] = s;
        counts[tid] = s;
    }
    __syncthreads();
    if (tid == 0) {
        int r = 0, g = 0, d = 0;
        for (int e = 0; e < 16; e++) {
            offs_s[e] = r;
            offsets[e] = r;
            r += totals[e];
            guPref[e] = g;
            g += ((totals[e] + 127) >> 7) * 8;  // 8 y128 panels (IDIM)
            dPref[e] = d;
            d += ((totals[e] + 255) >> 8) * 32;
        }
    }
    // shared-GEMM items (supertiles of 16 consecutive items)
    if (tid < 512) {  // GU shared: 32 mtiles x 16 y128 = 512 items
        int i = tid;
        int g = i >> 4, s = i & 15;
        int y0 = (g >> 3) << 2, m0 = (g & 7) << 2;
        itemsGU[i] = ((m0 + (s >> 2)) << 8) | (y0 + (s & 3));
    }
    if (tid < 512) {  // D shared: 16 mtiles x 32 y64 = 512 items
        int i = tid;
        int g = i >> 4, s = i & 15;
        int y0 = (g >> 2) << 2, m0 = (g & 3) << 2;
        itemsD[i] = ((m0 + (s >> 2)) << 8) | (y0 + (s & 3));
    }
    __syncthreads();
    // routed items + per-chunk bases (16 threads)
    if (tid < 16) {
        int e = tid;
        int tA = (totals[e] + 127) >> 7;
        int p = 512 + guPref[e];
        for (int y0 = 0; y0 < 8; y0 += 4)
            for (int m = 0; m < tA; m++)
                for (int dy = 0; dy < 4; dy++)
                    itemsGU[p++] = (1 << 28) | (e << 20) | (m << 8) | (y0 + dy);
        int tB = (totals[e] + 255) >> 8;
        p = 512 + dPref[e];
        for (int y0 = 0; y0 < 32; y0 += 4)
            for (int m = 0; m < tB; m++)
                for (int dy = 0; dy < 4; dy++)
                    itemsD[p++] = (1 << 28) | (e << 20) | (m << 8) | (y0 + dy);
        int r = offs_s[e];
        for (int c = 0; c < NCHUNK; c++) {
            int v = cnt[c][e];
            cnt[c][e] = r;
            r += v;
        }
    }
    __syncthreads();
    for (int c = wv; c < NCHUNK; c += 16) {
        int i = c * 64 + lane;
        int v = top_e[i];
        int rank = 0;
#pragma unroll
        for (int e = 0; e < 16; e++) {
            u64 m = __ballot(v == e);
            if (v == e) rank = (int)__popcll(m & ((1ull << lane) - 1ull));
        }
        int slot = cnt[c][v] + rank;
        list_tok[slot] = i >> 1;
        tok2slot[i] = slot;
    }
}

// ================= MAIN PATH =================
// ALL weight conversions in ONE dispatch (flat grid).
__global__ __launch_bounds__(256) void conv_all_kernel(
    const float* __restrict__ wgs, const float* __restrict__ wus,
    const float* __restrict__ wds, const float* __restrict__ wg,
    const float* __restrict__ wu, const float* __restrict__ wd, u16* __restrict__ Wt_gs,
    u16* __restrict__ Wt_us, u16* __restrict__ Wt_ds, u16* __restrict__ Wt_g,
    u16* __restrict__ Wt_u, u16* __restrict__ Wt_d) {
    int id = blockIdx.x;
    const float* Wm;
    u16* Wtm;
    int K, N, nt, kc;
    if (id < 768) {
        K = 2048; N = 2048;
        int seg = id >> 8, r = id & 255;
        nt = r & 31; kc = r >> 5;
        if (seg == 0) { Wm = wgs; Wtm = Wt_gs; }
        else if (seg == 1) { Wm = wus; Wtm = Wt_us; }
        else { Wm = wds; Wtm = Wt_ds; }
    } else if (id < 4864) {
        K = 2048; N = 1024;
        int r = id - 768;
        int m = r >> 11;
        r &= 2047;
        int e = r >> 7;
        r &= 127;
        nt = r & 15; kc = r >> 4;
        size_t off = (size_t)e * 2048 * 1024;
        if (m == 0) { Wm = wg + off; Wtm = Wt_g + off; }
        else { Wm = wu + off; Wtm = Wt_u + off; }
    } else {
        K = 1024; N = 2048;
        int r = id - 4864;
        int e = r >> 7;
        r &= 127;
        nt = r & 31; kc = r >> 5;
        size_t off = (size_t)e * 1024 * 2048;
        Wm = wd + off; Wtm = Wt_d + off;
    }
    int ksB = K >> 5;
    __shared__ u16 Ls[64 * 40];
    int t = threadIdx.x;
    int kr = t >> 3, ng = t & 7;
    int nn = t >> 2, seg2 = t & 3;
    int g = seg2 ^ ((nn >> 2) & 3);
#pragma unroll
    for (int s = 0; s < 8; s++) {
        int kb = kc * 256 + s * 32;
        const float* src = Wm + (size_t)(kb + kr) * N + nt * 64 + ng * 8;
        float4 f0 = *(const float4*)src;
        float4 f1 = *(const float4*)(src + 4);
        __syncthreads();
        const float* p0 = (const float*)&f0;
        const float* p1 = (const float*)&f1;
#pragma unroll
        for (int l = 0; l < 4; l++) Ls[(8 * ng + l) * 40 + kr] = f2b(p0[l]);
#pragma unroll
        for (int l = 0; l < 4; l++) Ls[(8 * ng + 4 + l) * 40 + kr] = f2b(p1[l]);
        __syncthreads();
        const u16* lp = &Ls[nn * 40 + g * 8];
        u32 w0 = (u32)lp[0] | ((u32)lp[1] << 16);
        u32 w1 = (u32)lp[2] | ((u32)lp[3] << 16);
        u32 w2 = (u32)lp[4] | ((u32)lp[5] << 16);
        u32 w3 = (u32)lp[6] | ((u32)lp[7] << 16);
        uint4 o = make_uint4(w0, w1, w2, w3);
        *(uint4*)(Wtm + (size_t)(nt * ksB + (kb >> 5)) * 2048 + t * 8) = o;
    }
}

// merged fused gate+up: M-tile 128, N-tile 128 PER MATRIX, BK 64, 8 waves.
// Waves 0-3 compute gate, 4-7 compute up; each wave acc[2][8] = 64 AGPR (+~52
// arch = ~116 <= 128 -> 4 waves/SIMD). 256 MFMA per block-step on 48KB staged
// (vs r10: 128 MFMA on 32KB) -> halves the synchronized-step count (the proven
// lever; r10 showed occupancy alone is NOT the constraint).
// Epilogue u-exchange reuses the first 32KB of staging LDS (2 passes of f32
// [128][64]) - no extra LDS.
__global__ __launch_bounds__(512, 4) void gemm_gateup(
    const u16* __restrict__ A, const u16* __restrict__ BgS, const u16* __restrict__ BuS,
    const u16* __restrict__ BgR, const u16* __restrict__ BuR, u16* __restrict__ hS,
    u16* __restrict__ hR, const int* __restrict__ counts, const int* __restrict__ offsets,
    const int* __restrict__ list_tok, const int* __restrict__ items) {
    int it = items[item_index(blockIdx.x)];
    if (it < 0) return;
    int routed = (it >> 28) & 1;
    int e = (it >> 20) & 15;
    int m0 = ((it >> 8) & 4095) * 128;
    int yb = it & 255;  // y-panel of 128
    int cnt, base, Nout;
    u16* hout;
    const u16 *BgBase, *BuBase;
    if (routed) {
        cnt = counts[e];
        base = offsets[e];
        Nout = IDIM;
        size_t off = (size_t)e * HDIM * IDIM;
        BgBase = BgR + off;
        BuBase = BuR + off;
        hout = hR;
    } else {
        cnt = TOKENS;
        base = 0;
        Nout = ISH;
        BgBase = BgS;
        BuBase = BuS;
        hout = hS;
    }
    const int nk = HDIM >> 6;  // BK=64 steps
    __shared__ alignas(16) u16 smem[24576];  // As 16KB | Bgs 16KB | Bus 16KB
    u16* As = smem;
    u16* Bgs = smem + 8192;
    u16* Bus = smem + 16384;
    float* us = (float*)smem;  // epilogue reuse (32KB of the 48KB)
    int tid = threadIdx.x;
    int lane = tid & 63, wv = tid >> 6;  // 8 waves
    int wl = wv & 3, mat = wv >> 2;      // mat: 0=gate, 1=up
    int quad = lane >> 4, mr = lane & 15;
    int gk = (tid & 3) ^ ((tid >> 4) & 3);
    int mg0 = min(m0 + (tid >> 2), cnt - 1);
    size_t sr0 = routed ? (size_t)list_tok[base + mg0] : (size_t)mg0;
    const u16* ap0 = A + sr0 * HDIM + gk * 8;  // thread stages A row tid>>2
    size_t bstr = (size_t)(HDIM >> 5) * 2048;  // per-n64-block stride
    int t4 = tid & 255;
    const u16* Bsel = mat ? BuBase : BgBase;
    const u16* bsrc0 = Bsel + (size_t)(2 * yb) * bstr + (size_t)t4 * 8;  // h=0
    const u16* bsrc1 = bsrc0 + bstr;                                     // h=1
    u16* bb = mat ? Bus : Bgs;
    u16* bdst = bb + wl * 512;  // wave-uniform base (+HW lane*16B)
    u16* adst = As + wv * 512;
    int xq = quad ^ ((mr >> 2) & 3);
    f32x4 acc[2][8];
#pragma unroll
    for (int i = 0; i < 2; i++)
#pragma unroll
        for (int j = 0; j < 8; j++) acc[i][j] = (f32x4)0.f;

    for (int ks = 0; ks < nk; ks++) {
        __syncthreads();
        __builtin_amdgcn_global_load_lds(AS1(ap0), AS3(adst), 16, 0, 0);
        __builtin_amdgcn_global_load_lds(AS1(ap0 + 32), AS3(adst + 4096), 16, 0, 0);
        __builtin_amdgcn_global_load_lds(AS1(bsrc0), AS3(bdst), 16, 0, 0);
        __builtin_amdgcn_global_load_lds(AS1(bsrc0 + 2048), AS3(bdst + 2048), 16, 0, 0);
        __builtin_amdgcn_global_load_lds(AS1(bsrc1), AS3(bdst + 4096), 16, 0, 0);
        __builtin_amdgcn_global_load_lds(AS1(bsrc1 + 2048), AS3(bdst + 6144), 16, 0, 0);
        ap0 += 64;
        bsrc0 += 4096;
        bsrc1 += 4096;
        __syncthreads();
#pragma unroll
        for (int c = 0; c < 2; c++) {
            short8 a0 = *(const short8*)(As + c * 4096 + ((32 * wl + mr) * 4 + xq) * 8);
            short8 a1 = *(const short8*)(As + c * 4096 + ((32 * wl + 16 + mr) * 4 + xq) * 8);
#pragma unroll
            for (int j = 0; j < 8; j++) {
                int h = j >> 2, jj = j & 3;
                short8 b = *(const short8*)(bb + h * 4096 + c * 2048 +
                                            (64 * jj + mr * 4 + xq) * 8);
                acc[0][j] = __builtin_amdgcn_mfma_f32_16x16x32_bf16(a0, b, acc[0][j], 0, 0, 0);
                acc[1][j] = __builtin_amdgcn_mfma_f32_16x16x32_bf16(a1, b, acc[1][j], 0, 0, 0);
            }
        }
    }
    // epilogue: two half-passes of 64 cols through the 32KB us buffer.
#pragma unroll
    for (int p = 0; p < 2; p++) {
        __syncthreads();
        if (mat == 1) {
#pragma unroll
            for (int i = 0; i < 2; i++)
#pragma unroll
                for (int jj = 0; jj < 4; jj++)
#pragma unroll
                    for (int r = 0; r < 4; r++) {
                        int row = 32 * wl + 16 * i + quad * 4 + r;
                        us[row * 64 + 16 * jj + mr] = acc[i][4 * p + jj][r];
                    }
        }
        __syncthreads();
        if (mat == 0) {
#pragma unroll
            for (int i = 0; i < 2; i++)
#pragma unroll
                for (int jj = 0; jj < 4; jj++)
#pragma unroll
                    for (int r = 0; r < 4; r++) {
                        int row = 32 * wl + 16 * i + quad * 4 + r;
                        int m = m0 + row;
                        if (m < cnt) {
                            float gv = acc[i][4 * p + jj][r];
                            float uv = us[row * 64 + 16 * jj + mr];
                            float h = gv / (1.f + expf(-gv)) * uv;
                            int n = yb * 128 + p * 64 + 16 * jj + mr;
                            hout[(size_t)(base + m) * Nout + n] = f2b(h);
                        }
                    }
        }
    }
}

// merged down GEMM (shared + routed): M-tile 256, N-tile 64, BK 64. (unchanged)
__global__ __launch_bounds__(256) void gemm_down(
    const u16* __restrict__ hS, const u16* __restrict__ hR, const u16* __restrict__ BdS,
    const u16* __restrict__ BdR, float* __restrict__ out, float* __restrict__ rd,
    const int* __restrict__ counts, const int* __restrict__ offsets,
    const int* __restrict__ items) {
    int it = items[item_index(blockIdx.x)];
    if (it < 0) return;
    int routed = (it >> 28) & 1;
    int e = (it >> 20) & 15;
    int m0 = ((it >> 8) & 4095) * 256;
    int yb = it & 255;
    int cnt, base, Kd;
    const u16 *A, *B;
    float* outp;
    if (routed) {
        cnt = counts[e];
        base = offsets[e];
        Kd = IDIM;
        A = hR;
        B = BdR + (size_t)e * IDIM * HDIM;
        outp = rd;
    } else {
        cnt = TOKENS;
        base = 0;
        Kd = ISH;
        A = hS;
        B = BdS;
        outp = out;
    }
    int nk = Kd >> 6;  // BK=64
    __shared__ alignas(16) u16 As[256 * 64];
    __shared__ alignas(16) u16 Bs[64 * 64];
    int tid = threadIdx.x;
    int lane = tid & 63, wv = tid >> 6;
    int quad = lane >> 4, mr = lane & 15;
    int n0 = yb * 64;
    int gk = (tid & 3) ^ ((tid >> 4) & 3);
    const u16* ap0;
    const u16* ap1;
    const u16* ap2;
    const u16* ap3;
    {
        int mg0 = base + min(m0 + 0 * 64 + (tid >> 2), cnt - 1);
        int mg1 = base + min(m0 + 1 * 64 + (tid >> 2), cnt - 1);
        int mg2 = base + min(m0 + 2 * 64 + (tid >> 2), cnt - 1);
        int mg3 = base + min(m0 + 3 * 64 + (tid >> 2), cnt - 1);
        ap0 = A + (size_t)mg0 * Kd + gk * 8;
        ap1 = A + (size_t)mg1 * Kd + gk * 8;
        ap2 = A + (size_t)mg2 * Kd + gk * 8;
        ap3 = A + (size_t)mg3 * Kd + gk * 8;
    }
    size_t bstr = (size_t)(Kd >> 5) * 2048;
    const u16* bp = B + (size_t)yb * bstr + tid * 8;
    int xq = quad ^ ((mr >> 2) & 3);
    f32x4 acc[4][4];
#pragma unroll
    for (int i = 0; i < 4; i++)
#pragma unroll
        for (int j = 0; j < 4; j++) acc[i][j] = (f32x4)0.f;

    for (int ks = 0; ks < nk; ks++) {
        __syncthreads();
        __builtin_amdgcn_global_load_lds(AS1(ap0), AS3(As + 0 + wv * 512), 16, 0, 0);
        __builtin_amdgcn_global_load_lds(AS1(ap0 + 32), AS3(As + 8192 + wv * 512), 16, 0, 0);
        __builtin_amdgcn_global_load_lds(AS1(ap1), AS3(As + 2048 + wv * 512), 16, 0, 0);
        __builtin_amdgcn_global_load_lds(AS1(ap1 + 32), AS3(As + 10240 + wv * 512), 16, 0, 0);
        __builtin_amdgcn_global_load_lds(AS1(ap2), AS3(As + 4096 + wv * 512), 16, 0, 0);
        __builtin_amdgcn_global_load_lds(AS1(ap2 + 32), AS3(As + 12288 + wv * 512), 16, 0, 0);
        __builtin_amdgcn_global_load_lds(AS1(ap3), AS3(As + 6144 + wv * 512), 16, 0, 0);
        __builtin_amdgcn_global_load_lds(AS1(ap3 + 32), AS3(As + 14336 + wv * 512), 16, 0, 0);
        __builtin_amdgcn_global_load_lds(AS1(bp), AS3(Bs + wv * 512), 16, 0, 0);
        __builtin_amdgcn_global_load_lds(AS1(bp + 2048), AS3(Bs + 2048 + wv * 512), 16, 0, 0);
        ap0 += 64; ap1 += 64; ap2 += 64; ap3 += 64; bp += 4096;
        __syncthreads();
#pragma unroll
        for (int c = 0; c < 2; c++) {
            short8 a0 = *(const short8*)(As + c * 8192 + ((64 * wv + 0 + mr) * 4 + xq) * 8);
            short8 a1 = *(const short8*)(As + c * 8192 + ((64 * wv + 16 + mr) * 4 + xq) * 8);
            short8 a2 = *(const short8*)(As + c * 8192 + ((64 * wv + 32 + mr) * 4 + xq) * 8);
            short8 a3 = *(const short8*)(As + c * 8192 + ((64 * wv + 48 + mr) * 4 + xq) * 8);
#pragma unroll
            for (int j = 0; j < 4; j++) {
                short8 b = *(const short8*)(Bs + c * 2048 + (64 * j + mr * 4 + xq) * 8);
                acc[0][j] = __builtin_amdgcn_mfma_f32_16x16x32_bf16(a0, b, acc[0][j], 0, 0, 0);
                acc[1][j] = __builtin_amdgcn_mfma_f32_16x16x32_bf16(a1, b, acc[1][j], 0, 0, 0);
                acc[2][j] = __builtin_amdgcn_mfma_f32_16x16x32_bf16(a2, b, acc[2][j], 0, 0, 0);
                acc[3][j] = __builtin_amdgcn_mfma_f32_16x16x32_bf16(a3, b, acc[3][j], 0, 0, 0);
            }
        }
    }

#pragma unroll
    for (int i = 0; i < 4; i++)
#pragma unroll
        for (int j = 0; j < 4; j++)
#pragma unroll
            for (int r = 0; r < 4; r++) {
                int m = m0 + 64 * wv + 16 * i + quad * 4 + r;
                if (m >= cnt) continue;
                int n = n0 + 16 * j + mr;
                float v = acc[i][j][r];
                if (routed) {
                    outp[(size_t)(base + m) * HDIM + n] = v;  // per-slot, no atomics
                } else {
                    outp[(size_t)m * HDIM + n] = 0.1f * v;
                }
            }
}

// ---------------- combine: out[t] += w0*rd[slot0] + w1*rd[slot1] ----------------
__global__ __launch_bounds__(256) void combine_kernel(float* __restrict__ out,
                                                      const float* __restrict__ rd,
                                                      const int* __restrict__ tok2slot,
                                                      const float* __restrict__ top_w) {
    int t = blockIdx.x;
    int s0 = tok2slot[2 * t], s1 = tok2slot[2 * t + 1];
    float w0 = top_w[2 * t], w1 = top_w[2 * t + 1];
    const float4* r0 = (const float4*)(rd + (size_t)s0 * HDIM);
    const float4* r1 = (const float4*)(rd + (size_t)s1 * HDIM);
    float4* op = (float4*)(out + (size_t)t * HDIM);
#pragma unroll
    for (int k = 0; k < 2; k++) {
        int c = threadIdx.x + k * 256;
        float4 o = op[c];
        float4 a = r0[c];
        float4 b = r1[c];
        o.x += w0 * a.x + w1 * b.x;
        o.y += w0 * a.y + w1 * b.y;
        o.z += w0 * a.z + w1 * b.z;
        o.w += w0 * a.w + w1 * b.w;
        op[c] = o;
    }
}

extern "C" void kernel_launch(void* const* d_in, const int* in_sizes, int n_in,
                              void* d_out, int out_size, void* d_ws, size_t ws_size,
                              hipStream_t stream) {
    const float* x = (const float*)d_in[0];
    const float* cent = (const float*)d_in[1];
    const float* bias = (const float*)d_in[2];
    const float* wgs = (const float*)d_in[3];
    const float* wus = (const float*)d_in[4];
    const float* wds = (const float*)d_in[5];
    const float* wg = (const float*)d_in[6];
    const float* wu = (const float*)d_in[7];
    const float* wd = (const float*)d_in[8];
    float* out = (float*)d_out;
    char* ws = (char*)d_ws;

    size_t off_wtgs = 0;
    size_t off_wtus = off_wtgs + (size_t)HDIM * ISH * 2;
    size_t off_wtds = off_wtus + (size_t)HDIM * ISH * 2;
    size_t off_wtg = off_wtds + (size_t)ISH * HDIM * 2;
    size_t off_wtu = off_wtg + (size_t)NEXP * HDIM * IDIM * 2;
    size_t off_wtd = off_wtu + (size_t)NEXP * HDIM * IDIM * 2;
    size_t off_xbf = off_wtd + (size_t)NEXP * IDIM * HDIM * 2;
    size_t off_hsh = off_xbf + (size_t)TOKENS * HDIM * 2;
    size_t off_hrt = off_hsh + (size_t)TOKENS * ISH * 2;
    size_t off_meta = off_hrt + (size_t)2 * TOKENS * IDIM * 2;
    size_t need = off_meta + (1 << 20);
    if (ws_size < need) return;  // main path verified present in round 2

    u16* Wt_gs = (u16*)(ws + off_wtgs);
    u16* Wt_us = (u16*)(ws + off_wtus);
    u16* Wt_ds = (u16*)(ws + off_wtds);
    u16* Wt_g = (u16*)(ws + off_wtg);
    u16* Wt_u = (u16*)(ws + off_wtu);
    u16* Wt_d = (u16*)(ws + off_wtd);
    u16* x_bf = (u16*)(ws + off_xbf);
    u16* h_sh = (u16*)(ws + off_hsh);
    u16* h_rt = (u16*)(ws + off_hrt);
    // rd (67 MB, f32 [8192][2048]) at off_wtg: overlaps routed gate/up weights
    // only; their last reader (merged gateup) completes before gemm_down writes
    // rd. conv_all rewrites the weights next iteration.
    float* rd = (float*)(ws + off_wtg);
    int* counts = (int*)(ws + off_meta);
    int* offsets = counts + 16;
    int* itemsGU = offsets + 16;
    int* itemsD = itemsGU + GUITEMS;
    int* tok2slot = itemsD + DITEMS;
    int* top_e = tok2slot + 2 * TOKENS;
    float* top_w = (float*)(top_e + 2 * TOKENS);
    int* list_tok = (int*)(top_w + 2 * TOKENS);

    route_kernel<<<TOKENS / 4, 256, 0, stream>>>(x, cent, bias, x_bf, top_e, top_w);
    build_kernel<<<1, 1024, 0, stream>>>(top_e, top_w, counts, offsets, itemsGU, itemsD,
                                         list_tok, tok2slot);
    conv_all_kernel<<<6912, 256, 0, stream>>>(wgs, wus, wds, wg, wu, wd, Wt_gs, Wt_us,
                                              Wt_ds, Wt_g, Wt_u, Wt_d);
    gemm_gateup<<<GUITEMS, 512, 0, stream>>>(x_bf, Wt_gs, Wt_us, Wt_g, Wt_u, h_sh, h_rt,
                                             counts, offsets, list_tok, itemsGU);
    gemm_down<<<DITEMS, 256, 0, stream>>>(h_sh, h_rt, Wt_ds, Wt_d, out, rd, counts,
                                          offsets, itemsD);
    combine_kernel<<<TOKENS, 256, 0, stream>>>(out, rd, tok2slot, top_w);
}